// Round 8
// baseline (464.877 us; speedup 1.0000x reference)
//
#include <hip/hip_runtime.h>
#include <hip/hip_bf16.h>
#include <math.h>

#define NODES 50000
#define EDGES 10000
#define NNZ   800000
#define FIN   128
#define NHID  128
#define FOUT  64

#define HV 4   // heads per vertex (deg ~16 -> chains ~4)
#define HE 8   // heads per edge   (deg ~80 -> chains ~10)

#define BUILD_BLOCKS (NNZ / 256)          // 3125
#define WCONV_BLOCKS 128
#define GEMM_BLOCKS  ((NODES + 63) / 64)  // 782
#define EDGE_BLOCKS  (EDGES * 64 / 256)   // 2500
#define NODE_BLOCKS  (NODES * 64 / 256)   // 12500

typedef __attribute__((ext_vector_type(8))) short bf16x8;
typedef __attribute__((ext_vector_type(4))) float f32x4;
typedef unsigned short ushort_t;

__device__ __forceinline__ ushort_t f2b(float f) {
    __hip_bfloat16 h = __float2bfloat16(f);
    return *reinterpret_cast<ushort_t*>(&h);
}
__device__ __forceinline__ float u2f(unsigned u) {
    union { unsigned u; float f; } c; c.u = u; return c.f;
}

// ---- K1: build vertex linked lists (atomicExch) | weight transpose/convert ----
__global__ __launch_bounds__(256)
void buildv_wconv_kernel(const int* __restrict__ vertex,
                         int* __restrict__ head_v, int* __restrict__ next_v,
                         const float* __restrict__ W0, const float* __restrict__ Ws,
                         const float* __restrict__ Wout,
                         ushort_t* __restrict__ Wt0, ushort_t* __restrict__ WsT,
                         ushort_t* __restrict__ WoutT) {
    if (blockIdx.x < BUILD_BLOCKS) {
        const int i = blockIdx.x * 256 + threadIdx.x;
        const int v = vertex[i];
        next_v[i] = atomicExch(&head_v[v * HV + (i & (HV - 1))], i);
    } else {
        const int i = (blockIdx.x - BUILD_BLOCKS) * 256 + threadIdx.x;
        if (i < 128 * 128) { int c = i >> 7, k = i & 127; Wt0[c * 128 + k] = f2b(W0[k * 128 + c]); }
        if (i < 2 * 128 * 128) {
            int l = i >> 14, r = i & 16383, c = r >> 7, k = r & 127;
            WsT[l * 16384 + c * 128 + k] = f2b(Ws[l * 16384 + k * 128 + c]);
        }
        if (i < 64 * 128) { int c = i >> 7, k = i & 127; WoutT[c * 128 + k] = f2b(Wout[k * 64 + c]); }
    }
}

// ---- K2: build edge linked lists | input GEMM (MFMA) x = x0 = relu(Xin@W0+b0) ----
__global__ __launch_bounds__(256)
void builde_gemm_kernel(const int* __restrict__ edges,
                        int* __restrict__ head_e, int* __restrict__ next_e,
                        const float* __restrict__ X, const ushort_t* __restrict__ Wt,
                        const float* __restrict__ bias,
                        ushort_t* __restrict__ x, ushort_t* __restrict__ x0) {
    if (blockIdx.x < BUILD_BLOCKS) {
        const int i = blockIdx.x * 256 + threadIdx.x;
        const int e = edges[i];
        next_e[i] = atomicExch(&head_e[e * HE + (i & (HE - 1))], i);
        return;
    }
    const int lane = threadIdx.x & 63, wave = threadIdx.x >> 6;
    const int row0 = (blockIdx.x - BUILD_BLOCKS) * 64 + wave * 16;
    if (row0 >= NODES) return;
    const int r = lane & 15, kb = lane >> 4;
    const int row = row0 + r;
    bf16x8 a[4];
#pragma unroll
    for (int k0 = 0; k0 < 4; ++k0) {
        const float* p = X + (size_t)row * FIN + k0 * 32 + kb * 8;
        const float4 lo = *(const float4*)p;
        const float4 hi = *(const float4*)(p + 4);
        bf16x8 t;
        t[0] = f2b(lo.x); t[1] = f2b(lo.y); t[2] = f2b(lo.z); t[3] = f2b(lo.w);
        t[4] = f2b(hi.x); t[5] = f2b(hi.y); t[6] = f2b(hi.z); t[7] = f2b(hi.w);
        a[k0] = t;
    }
    f32x4 acc[8];
#pragma unroll
    for (int c0 = 0; c0 < 8; ++c0) {
        const float bv = bias[c0 * 16 + r];
        acc[c0] = (f32x4){bv, bv, bv, bv};
    }
#pragma unroll
    for (int k0 = 0; k0 < 4; ++k0)
#pragma unroll
        for (int c0 = 0; c0 < 8; ++c0) {
            const bf16x8 b = *(const bf16x8*)(Wt + (size_t)(c0 * 16 + r) * FIN + k0 * 32 + kb * 8);
            acc[c0] = __builtin_amdgcn_mfma_f32_16x16x32_bf16(a[k0], b, acc[c0], 0, 0, 0);
        }
#pragma unroll
    for (int c0 = 0; c0 < 8; ++c0) {
        const int col = c0 * 16 + r;
#pragma unroll
        for (int v = 0; v < 4; ++v) {
            const int orow = row0 + kb * 4 + v;
            float val = acc[c0][v];
            val = val > 0.f ? val : 0.f;
            const ushort_t ub = f2b(val);
            x [(size_t)orow * NHID + col] = ub;
            x0[(size_t)orow * NHID + col] = ub;
        }
    }
}

// ---- edge gather + mean via HE-chain walk: one wave per edge; Xe bf16; opt f32 out ----
__global__ __launch_bounds__(256)
void edge_gather_kernel(const ushort_t* __restrict__ x,
                        const int* __restrict__ head_e, const int* __restrict__ next_e,
                        const int* __restrict__ vertex,
                        ushort_t* __restrict__ Xe, float* __restrict__ out_xe) {
    const int e = (blockIdx.x * 256 + (int)threadIdx.x) >> 6;
    const int lane = threadIdx.x & 63;
    if (e >= EDGES) return;
    int p[HE];
#pragma unroll
    for (int c = 0; c < HE; ++c) p[c] = head_e[e * HE + c];
    float a0 = 0.f, a1 = 0.f;
    int cnt = 0;
    while (true) {
        int vtx[HE], nxt[HE];
        bool any = false;
#pragma unroll
        for (int c = 0; c < HE; ++c)
            if (p[c] >= 0) { vtx[c] = vertex[p[c]]; nxt[c] = next_e[p[c]]; any = true; }
        if (!any) break;
#pragma unroll
        for (int c = 0; c < HE; ++c)
            if (p[c] >= 0) {
                const unsigned u = *(const unsigned*)(x + (size_t)vtx[c] * NHID + 2 * lane);
                a0 += u2f(u << 16);
                a1 += u2f(u & 0xffff0000u);
                ++cnt;
                p[c] = nxt[c];
            }
    }
    const float inv = 1.f / (float)max(cnt, 1);
    const float v0 = a0 * inv, v1 = a1 * inv;
    const unsigned lo = f2b(v0), hi = f2b(v1);
    *(unsigned*)(Xe + (size_t)e * NHID + 2 * lane) = lo | (hi << 16);
    if (out_xe) {
        const float2 v = {v0, v1};
        *(float2*)(out_xe + (size_t)e * NHID + 2 * lane) = v;
    }
}

// ---- node gather + mean + L2-normalize + residual via HV-chain walk ----
__global__ __launch_bounds__(256)
void node_gather_post_kernel(const ushort_t* __restrict__ Xe,
                             const int* __restrict__ head_v, const int* __restrict__ next_v,
                             const int* __restrict__ edges,
                             const ushort_t* __restrict__ x0, ushort_t* __restrict__ x) {
    const int v = (blockIdx.x * 256 + (int)threadIdx.x) >> 6;
    const int lane = threadIdx.x & 63;
    if (v >= NODES) return;
    int p[HV];
#pragma unroll
    for (int c = 0; c < HV; ++c) p[c] = head_v[v * HV + c];
    float a0 = 0.f, a1 = 0.f;
    int cnt = 0;
    while (true) {
        int eid[HV], nxt[HV];
        bool any = false;
#pragma unroll
        for (int c = 0; c < HV; ++c)
            if (p[c] >= 0) { eid[c] = edges[p[c]]; nxt[c] = next_v[p[c]]; any = true; }
        if (!any) break;
#pragma unroll
        for (int c = 0; c < HV; ++c)
            if (p[c] >= 0) {
                const unsigned u = *(const unsigned*)(Xe + (size_t)eid[c] * NHID + 2 * lane);
                a0 += u2f(u << 16);
                a1 += u2f(u & 0xffff0000u);
                ++cnt;
                p[c] = nxt[c];
            }
    }
    const float inv = 1.f / (float)max(cnt, 1);
    const float m0 = a0 * inv, m1 = a1 * inv;
    float s = m0 * m0 + m1 * m1;
#pragma unroll
    for (int o = 32; o > 0; o >>= 1) s += __shfl_xor(s, o);
    const float norm = sqrtf(s);
    const float scale = norm > 0.f ? 1.f / fmaxf(norm, 1e-30f) : 0.f;
    const size_t off = (size_t)v * NHID + 2 * lane;
    const unsigned ux0 = *(const unsigned*)(x0 + off);
    const float x00 = u2f(ux0 << 16);
    const float x01 = u2f(ux0 & 0xffff0000u);
    const unsigned lo = f2b(0.9f * m0 * scale + 0.1f * x00);
    const unsigned hi = f2b(0.9f * m1 * scale + 0.1f * x01);
    *(unsigned*)(x + off) = lo | (hi << 16);
}

// ---- layer GEMM (MFMA, in place): x = relu((1-beta)*x + beta*(x @ W)) ----
__global__ __launch_bounds__(256)
void layer_gemm_kernel(ushort_t* __restrict__ x, const ushort_t* __restrict__ Wt, float beta) {
    const int lane = threadIdx.x & 63, wave = threadIdx.x >> 6;
    const int row0 = blockIdx.x * 64 + wave * 16;
    if (row0 >= NODES) return;
    const int r = lane & 15, kb = lane >> 4;
    const int row = row0 + r;
    bf16x8 a[4];
#pragma unroll
    for (int k0 = 0; k0 < 4; ++k0)
        a[k0] = *(const bf16x8*)(x + (size_t)row * NHID + k0 * 32 + kb * 8);
    f32x4 acc[8] = {};
#pragma unroll
    for (int k0 = 0; k0 < 4; ++k0)
#pragma unroll
        for (int c0 = 0; c0 < 8; ++c0) {
            const bf16x8 b = *(const bf16x8*)(Wt + (size_t)(c0 * 16 + r) * NHID + k0 * 32 + kb * 8);
            acc[c0] = __builtin_amdgcn_mfma_f32_16x16x32_bf16(a[k0], b, acc[c0], 0, 0, 0);
        }
    const float xi_m = 1.f - beta;
#pragma unroll
    for (int c0 = 0; c0 < 8; ++c0) {
        const int col = c0 * 16 + r;
#pragma unroll
        for (int v = 0; v < 4; ++v) {
            const int orow = row0 + kb * 4 + v;
            const size_t off = (size_t)orow * NHID + col;
            union { ushort_t u; __hip_bfloat16 b; } cv; cv.u = x[off];
            const float xi = __bfloat162float(cv.b);
            float val = xi_m * xi + beta * acc[c0][v];
            val = val > 0.f ? val : 0.f;
            x[off] = f2b(val);
        }
    }
}

// ---- output GEMM (MFMA): out = x @ Wout + bout (f32 out) ----
__global__ __launch_bounds__(256)
void out_gemm_kernel(const ushort_t* __restrict__ x, const ushort_t* __restrict__ Wt,
                     const float* __restrict__ bias, float* __restrict__ out) {
    const int lane = threadIdx.x & 63, wave = threadIdx.x >> 6;
    const int row0 = blockIdx.x * 64 + wave * 16;
    if (row0 >= NODES) return;
    const int r = lane & 15, kb = lane >> 4;
    const int row = row0 + r;
    bf16x8 a[4];
#pragma unroll
    for (int k0 = 0; k0 < 4; ++k0)
        a[k0] = *(const bf16x8*)(x + (size_t)row * NHID + k0 * 32 + kb * 8);
    f32x4 acc[4];
#pragma unroll
    for (int c0 = 0; c0 < 4; ++c0) {
        const float bv = bias[c0 * 16 + r];
        acc[c0] = (f32x4){bv, bv, bv, bv};
    }
#pragma unroll
    for (int k0 = 0; k0 < 4; ++k0)
#pragma unroll
        for (int c0 = 0; c0 < 4; ++c0) {
            const bf16x8 b = *(const bf16x8*)(Wt + (size_t)(c0 * 16 + r) * NHID + k0 * 32 + kb * 8);
            acc[c0] = __builtin_amdgcn_mfma_f32_16x16x32_bf16(a[k0], b, acc[c0], 0, 0, 0);
        }
#pragma unroll
    for (int c0 = 0; c0 < 4; ++c0) {
        const int col = c0 * 16 + r;
#pragma unroll
        for (int v = 0; v < 4; ++v) {
            const int orow = row0 + kb * 4 + v;
            out[(size_t)orow * FOUT + col] = acc[c0][v];
        }
    }
}

extern "C" void kernel_launch(void* const* d_in, const int* in_sizes, int n_in,
                              void* d_out, int out_size, void* d_ws, size_t ws_size,
                              hipStream_t stream) {
    const float* x_in  = (const float*)d_in[0];
    const float* W0    = (const float*)d_in[1];
    const float* b0    = (const float*)d_in[2];
    const float* Ws    = (const float*)d_in[3];
    const float* Wout  = (const float*)d_in[4];
    const float* bout  = (const float*)d_in[5];
    const int* vertex  = (const int*)d_in[6];
    const int* edges   = (const int*)d_in[7];

    ushort_t* Xe   = (ushort_t*)d_ws;                       // EDGES*NHID bf16 (2.56 MB)
    ushort_t* x    = Xe + (size_t)EDGES * NHID;             // NODES*NHID bf16
    ushort_t* x0   = x  + (size_t)NODES * NHID;             // NODES*NHID bf16
    ushort_t* Wt0  = x0 + (size_t)NODES * NHID;             // 128*128
    ushort_t* WsT  = Wt0 + 128 * 128;                       // 2*128*128
    ushort_t* WoutT= WsT + 2 * 128 * 128;                   // 64*128
    int* head_v = (int*)(WoutT + 64 * 128);                 // NODES*HV   } contiguous,
    int* head_e = head_v + NODES * HV;                      // EDGES*HE   } one 0xFF memset
    int* next_v = head_e + EDGES * HE;                      // NNZ
    int* next_e = next_v + NNZ;                             // NNZ

    float* out    = (float*)d_out;                          // [NODES, FOUT]
    float* out_xe = out + (size_t)NODES * FOUT;             // [EDGES, NHID]

    // heads = -1
    hipMemsetAsync(head_v, 0xFF, (size_t)(NODES * HV + EDGES * HE) * sizeof(int), stream);

    // K1: vertex linked lists + weight conversion
    buildv_wconv_kernel<<<BUILD_BLOCKS + WCONV_BLOCKS, 256, 0, stream>>>(
        vertex, head_v, next_v, W0, Ws, Wout, Wt0, WsT, WoutT);
    // K2: edge linked lists + input GEMM
    builde_gemm_kernel<<<BUILD_BLOCKS + GEMM_BLOCKS, 256, 0, stream>>>(
        edges, head_e, next_e, x_in, Wt0, b0, x, x0);

    const float betas[2] = {logf(1.5f), logf(1.25f)};  // log(0.5/(i+1)+1)

    // layer 1
    edge_gather_kernel<<<EDGE_BLOCKS, 256, 0, stream>>>(x, head_e, next_e, vertex,
                                                        Xe, (float*)nullptr);
    node_gather_post_kernel<<<NODE_BLOCKS, 256, 0, stream>>>(Xe, head_v, next_v, edges, x0, x);
    layer_gemm_kernel<<<GEMM_BLOCKS, 256, 0, stream>>>(x, WsT, betas[0]);

    // layer 2
    edge_gather_kernel<<<EDGE_BLOCKS, 256, 0, stream>>>(x, head_e, next_e, vertex,
                                                        Xe, out_xe);
    node_gather_post_kernel<<<NODE_BLOCKS, 256, 0, stream>>>(Xe, head_v, next_v, edges, x0, x);
    layer_gemm_kernel<<<GEMM_BLOCKS, 256, 0, stream>>>(x, WsT + (size_t)NHID * NHID, betas[1]);

    out_gemm_kernel<<<GEMM_BLOCKS, 256, 0, stream>>>(x, WoutT, bout, out);
}

// Round 9
// 314.103 us; speedup vs baseline: 1.4800x; 1.4800x over previous
//
#include <hip/hip_runtime.h>
#include <hip/hip_bf16.h>
#include <math.h>

#define NODES 50000
#define EDGES 10000
#define NNZ   800000
#define FIN   128
#define NHID  128
#define FOUT  64

#define HIST_BLOCKS  (NNZ / 256)          // 3125
#define WCONV_BLOCKS 128
#define FILL_BLOCKS  (NNZ / 256)          // 3125
#define GEMM_BLOCKS  ((NODES + 63) / 64)  // 782
#define EDGE_BLOCKS  (EDGES * 64 / 256)   // 2500
#define NODE_BLOCKS  (NODES * 64 / 256)   // 12500

typedef __attribute__((ext_vector_type(8))) short bf16x8;
typedef __attribute__((ext_vector_type(4))) float f32x4;
typedef unsigned short ushort_t;

__device__ __forceinline__ ushort_t f2b(float f) {
    __hip_bfloat16 h = __float2bfloat16(f);
    return *reinterpret_cast<ushort_t*>(&h);
}
__device__ __forceinline__ float u2f(unsigned u) {
    union { unsigned u; float f; } c; c.u = u; return c.f;
}
__device__ __forceinline__ unsigned pk2(float lo, float hi) {
    return (unsigned)f2b(lo) | ((unsigned)f2b(hi) << 16);
}

// ---- K1: histogram+rank of EDGE keys | weight transpose/convert ----
__global__ __launch_bounds__(256)
void hist_e_wconv_kernel(const int* __restrict__ edges,
                         int* __restrict__ cnt_e, int* __restrict__ rank_e,
                         const float* __restrict__ W0, const float* __restrict__ Ws,
                         const float* __restrict__ Wout,
                         ushort_t* __restrict__ Wt0, ushort_t* __restrict__ WsT,
                         ushort_t* __restrict__ WoutT) {
    if (blockIdx.x < HIST_BLOCKS) {
        const int i = blockIdx.x * 256 + threadIdx.x;
        rank_e[i] = atomicAdd(&cnt_e[edges[i]], 1);
    } else {
        const int i = (blockIdx.x - HIST_BLOCKS) * 256 + threadIdx.x;
        if (i < 128 * 128) { int c = i >> 7, k = i & 127; Wt0[c * 128 + k] = f2b(W0[k * 128 + c]); }
        if (i < 2 * 128 * 128) {
            int l = i >> 14, r = i & 16383, c = r >> 7, k = r & 127;
            WsT[l * 16384 + c * 128 + k] = f2b(Ws[l * 16384 + k * 128 + c]);
        }
        if (i < 64 * 128) { int c = i >> 7, k = i & 127; WoutT[c * 128 + k] = f2b(Wout[k * 64 + c]); }
    }
}

// ---- exclusive scan, 8 items/thread, single 1024-thread block ----
__device__ __forceinline__ void scan_impl(const int* __restrict__ cnt, int* __restrict__ rp,
                                          const int n) {
    __shared__ int wsum[16];
    __shared__ int carry_sh;
    const int t = threadIdx.x, lane = t & 63, w = t >> 6;
    if (t == 0) carry_sh = 0;
    __syncthreads();
    for (int base = 0; base < n; base += 8192) {
        const int idx = base + t * 8;
        int v[8];
        if (idx + 8 <= n) {
            const int4 a = *(const int4*)(cnt + idx);
            const int4 b = *(const int4*)(cnt + idx + 4);
            v[0] = a.x; v[1] = a.y; v[2] = a.z; v[3] = a.w;
            v[4] = b.x; v[5] = b.y; v[6] = b.z; v[7] = b.w;
        } else {
#pragma unroll
            for (int j = 0; j < 8; ++j) v[j] = (idx + j < n) ? cnt[idx + j] : 0;
        }
        int sum8 = 0;
#pragma unroll
        for (int j = 0; j < 8; ++j) sum8 += v[j];
        int x = sum8;
#pragma unroll
        for (int o = 1; o < 64; o <<= 1) {
            int y = __shfl_up(x, o);
            if (lane >= o) x += y;
        }
        if (lane == 63) wsum[w] = x;
        __syncthreads();
        if (t < 16) {
            int s = wsum[t];
#pragma unroll
            for (int o = 1; o < 16; o <<= 1) {
                int y = __shfl_up(s, o);
                if (t >= o) s += y;
            }
            wsum[t] = s;
        }
        __syncthreads();
        const int carry = carry_sh;
        int pre = carry + (x - sum8) + (w ? wsum[w - 1] : 0);
        if (idx < n) {
#pragma unroll
            for (int j = 0; j < 8; ++j)
                if (idx + j < n) { rp[idx + j] = pre; pre += v[j]; }
        }
        __syncthreads();
        if (t == 1023) carry_sh = carry + wsum[15];
        __syncthreads();
    }
    if (t == 0) rp[n] = carry_sh;
}

__global__ __launch_bounds__(1024)
void scan_e_kernel(const int* __restrict__ cnt_e, int* __restrict__ rp_e) {
    scan_impl(cnt_e, rp_e, EDGES);
}
__global__ __launch_bounds__(1024)
void scan_v_kernel(const int* __restrict__ cnt_v, int* __restrict__ rp_v) {
    scan_impl(cnt_v, rp_v, NODES);
}

// ---- K3: fill edge-CSR + histogram vertex keys | input GEMM (MFMA) ----
__global__ __launch_bounds__(256)
void fille_histv_gemm_kernel(const int* __restrict__ vertex, const int* __restrict__ edges,
                             const int* __restrict__ rank_e, const int* __restrict__ rp_e,
                             int* __restrict__ col_e,
                             int* __restrict__ cnt_v, int* __restrict__ rank_v,
                             const float* __restrict__ X, const ushort_t* __restrict__ Wt,
                             const float* __restrict__ bias,
                             ushort_t* __restrict__ x, ushort_t* __restrict__ x0) {
    if (blockIdx.x < FILL_BLOCKS) {
        const int i = blockIdx.x * 256 + threadIdx.x;
        const int e = edges[i], v = vertex[i];
        col_e[rp_e[e] + rank_e[i]] = v;
        rank_v[i] = atomicAdd(&cnt_v[v], 1);
        return;
    }
    const int lane = threadIdx.x & 63, wave = threadIdx.x >> 6;
    const int row0 = (blockIdx.x - FILL_BLOCKS) * 64 + wave * 16;
    if (row0 >= NODES) return;
    const int r = lane & 15, kb = lane >> 4;
    const int row = row0 + r;
    bf16x8 a[4];
#pragma unroll
    for (int k0 = 0; k0 < 4; ++k0) {
        const float* p = X + (size_t)row * FIN + k0 * 32 + kb * 8;
        const float4 lo = *(const float4*)p;
        const float4 hi = *(const float4*)(p + 4);
        bf16x8 t;
        t[0] = f2b(lo.x); t[1] = f2b(lo.y); t[2] = f2b(lo.z); t[3] = f2b(lo.w);
        t[4] = f2b(hi.x); t[5] = f2b(hi.y); t[6] = f2b(hi.z); t[7] = f2b(hi.w);
        a[k0] = t;
    }
    f32x4 acc[8];
#pragma unroll
    for (int c0 = 0; c0 < 8; ++c0) {
        const float bv = bias[c0 * 16 + r];
        acc[c0] = (f32x4){bv, bv, bv, bv};
    }
#pragma unroll
    for (int k0 = 0; k0 < 4; ++k0)
#pragma unroll
        for (int c0 = 0; c0 < 8; ++c0) {
            const bf16x8 b = *(const bf16x8*)(Wt + (size_t)(c0 * 16 + r) * FIN + k0 * 32 + kb * 8);
            acc[c0] = __builtin_amdgcn_mfma_f32_16x16x32_bf16(a[k0], b, acc[c0], 0, 0, 0);
        }
#pragma unroll
    for (int c0 = 0; c0 < 8; ++c0) {
        const int col = c0 * 16 + r;
#pragma unroll
        for (int v = 0; v < 4; ++v) {
            const int orow = row0 + kb * 4 + v;
            float val = acc[c0][v];
            val = val > 0.f ? val : 0.f;
            const ushort_t ub = f2b(val);
            x [(size_t)orow * NHID + col] = ub;
            x0[(size_t)orow * NHID + col] = ub;
        }
    }
}

// ---- edge gather body: 16 lanes/row, uint4 loads, 4 rows in flight per wave ----
__device__ __forceinline__ void edge_gather_body(const int e,
                                                 const ushort_t* __restrict__ x,
                                                 const int* __restrict__ rp,
                                                 const int* __restrict__ ci,
                                                 ushort_t* __restrict__ Xe,
                                                 float* __restrict__ out_xe) {
    const int lane = threadIdx.x & 63;
    const int sub = lane >> 4, lr = lane & 15;
    const int beg = rp[e], end = rp[e + 1];
    float a[8] = {};
    for (int base = beg; base < end; base += 64) {
        const int m = min(64, end - base);
        const int idx_l = (lane < m) ? ci[base + lane] : 0;
        const int steps = (m + 3) >> 2;
#pragma unroll 4
        for (int j = 0; j < steps; ++j) {
            const int slot = j * 4 + sub;
            const int src = __shfl(idx_l, slot);
            if (slot < m) {
                const uint4 d = *(const uint4*)(x + (size_t)src * NHID + lr * 8);
                a[0] += u2f(d.x << 16); a[1] += u2f(d.x & 0xffff0000u);
                a[2] += u2f(d.y << 16); a[3] += u2f(d.y & 0xffff0000u);
                a[4] += u2f(d.z << 16); a[5] += u2f(d.z & 0xffff0000u);
                a[6] += u2f(d.w << 16); a[7] += u2f(d.w & 0xffff0000u);
            }
        }
    }
#pragma unroll
    for (int k = 0; k < 8; ++k) {
        a[k] += __shfl_xor(a[k], 16);
        a[k] += __shfl_xor(a[k], 32);
    }
    const float inv = 1.f / (float)max(end - beg, 1);
    if (sub == 0) {
        float vv[8];
#pragma unroll
        for (int k = 0; k < 8; ++k) vv[k] = a[k] * inv;
        uint4 o;
        o.x = pk2(vv[0], vv[1]); o.y = pk2(vv[2], vv[3]);
        o.z = pk2(vv[4], vv[5]); o.w = pk2(vv[6], vv[7]);
        *(uint4*)(Xe + (size_t)e * NHID + lr * 8) = o;
        if (out_xe) {
            const float4 f0 = {vv[0], vv[1], vv[2], vv[3]};
            const float4 f1 = {vv[4], vv[5], vv[6], vv[7]};
            *(float4*)(out_xe + (size_t)e * NHID + lr * 8) = f0;
            *(float4*)(out_xe + (size_t)e * NHID + lr * 8 + 4) = f1;
        }
    }
}

// ---- K5: fill vertex-CSR | edge gather (layer 1) ----
__global__ __launch_bounds__(256)
void fillv_edgegather_kernel(const int* __restrict__ vertex, const int* __restrict__ edges,
                             const int* __restrict__ rank_v, const int* __restrict__ rp_v,
                             int* __restrict__ col_v,
                             const ushort_t* __restrict__ x, const int* __restrict__ rp_e,
                             const int* __restrict__ col_e, ushort_t* __restrict__ Xe) {
    if (blockIdx.x < FILL_BLOCKS) {
        const int i = blockIdx.x * 256 + threadIdx.x;
        col_v[rp_v[vertex[i]] + rank_v[i]] = edges[i];
        return;
    }
    const int e = ((blockIdx.x - FILL_BLOCKS) * 256 + (int)threadIdx.x) >> 6;
    if (e >= EDGES) return;
    edge_gather_body(e, x, rp_e, col_e, Xe, (float*)nullptr);
}

// ---- edge gather standalone (layer 2, with f32 output copy) ----
__global__ __launch_bounds__(256)
void edge_gather_kernel(const ushort_t* __restrict__ x, const int* __restrict__ rp,
                        const int* __restrict__ ci, ushort_t* __restrict__ Xe,
                        float* __restrict__ out_xe) {
    const int e = (blockIdx.x * 256 + (int)threadIdx.x) >> 6;
    if (e >= EDGES) return;
    edge_gather_body(e, x, rp, ci, Xe, out_xe);
}

// ---- node gather + mean + L2-normalize + residual (16 lanes/row uint4) ----
__global__ __launch_bounds__(256)
void node_gather_post_kernel(const ushort_t* __restrict__ Xe, const int* __restrict__ rp,
                             const int* __restrict__ ci, const ushort_t* __restrict__ x0,
                             ushort_t* __restrict__ x) {
    const int v = (blockIdx.x * 256 + (int)threadIdx.x) >> 6;
    const int lane = threadIdx.x & 63;
    if (v >= NODES) return;
    const int sub = lane >> 4, lr = lane & 15;
    const int beg = rp[v], end = rp[v + 1];
    float a[8] = {};
    for (int base = beg; base < end; base += 64) {
        const int m = min(64, end - base);
        const int idx_l = (lane < m) ? ci[base + lane] : 0;
        const int steps = (m + 3) >> 2;
#pragma unroll 4
        for (int j = 0; j < steps; ++j) {
            const int slot = j * 4 + sub;
            const int src = __shfl(idx_l, slot);
            if (slot < m) {
                const uint4 d = *(const uint4*)(Xe + (size_t)src * NHID + lr * 8);
                a[0] += u2f(d.x << 16); a[1] += u2f(d.x & 0xffff0000u);
                a[2] += u2f(d.y << 16); a[3] += u2f(d.y & 0xffff0000u);
                a[4] += u2f(d.z << 16); a[5] += u2f(d.z & 0xffff0000u);
                a[6] += u2f(d.w << 16); a[7] += u2f(d.w & 0xffff0000u);
            }
        }
    }
#pragma unroll
    for (int k = 0; k < 8; ++k) {
        a[k] += __shfl_xor(a[k], 16);
        a[k] += __shfl_xor(a[k], 32);
    }
    const float inv = 1.f / (float)max(end - beg, 1);
    float mk[8];
    float s = 0.f;
#pragma unroll
    for (int k = 0; k < 8; ++k) { mk[k] = a[k] * inv; s += mk[k] * mk[k]; }
    s += __shfl_xor(s, 1); s += __shfl_xor(s, 2);
    s += __shfl_xor(s, 4); s += __shfl_xor(s, 8);
    const float norm = sqrtf(s);
    const float scale = norm > 0.f ? 1.f / fmaxf(norm, 1e-30f) : 0.f;
    if (sub == 0) {
        const uint4 u0 = *(const uint4*)(x0 + (size_t)v * NHID + lr * 8);
        float xv[8];
        xv[0] = u2f(u0.x << 16); xv[1] = u2f(u0.x & 0xffff0000u);
        xv[2] = u2f(u0.y << 16); xv[3] = u2f(u0.y & 0xffff0000u);
        xv[4] = u2f(u0.z << 16); xv[5] = u2f(u0.z & 0xffff0000u);
        xv[6] = u2f(u0.w << 16); xv[7] = u2f(u0.w & 0xffff0000u);
        float o[8];
#pragma unroll
        for (int k = 0; k < 8; ++k) o[k] = 0.9f * mk[k] * scale + 0.1f * xv[k];
        uint4 ou;
        ou.x = pk2(o[0], o[1]); ou.y = pk2(o[2], o[3]);
        ou.z = pk2(o[4], o[5]); ou.w = pk2(o[6], o[7]);
        *(uint4*)(x + (size_t)v * NHID + lr * 8) = ou;
    }
}

// ---- layer GEMM (MFMA, in place): x = relu((1-beta)*x + beta*(x @ W)) ----
__global__ __launch_bounds__(256)
void layer_gemm_kernel(ushort_t* __restrict__ x, const ushort_t* __restrict__ Wt, float beta) {
    const int lane = threadIdx.x & 63, wave = threadIdx.x >> 6;
    const int row0 = blockIdx.x * 64 + wave * 16;
    if (row0 >= NODES) return;
    const int r = lane & 15, kb = lane >> 4;
    const int row = row0 + r;
    bf16x8 a[4];
#pragma unroll
    for (int k0 = 0; k0 < 4; ++k0)
        a[k0] = *(const bf16x8*)(x + (size_t)row * NHID + k0 * 32 + kb * 8);
    f32x4 acc[8] = {};
#pragma unroll
    for (int k0 = 0; k0 < 4; ++k0)
#pragma unroll
        for (int c0 = 0; c0 < 8; ++c0) {
            const bf16x8 b = *(const bf16x8*)(Wt + (size_t)(c0 * 16 + r) * NHID + k0 * 32 + kb * 8);
            acc[c0] = __builtin_amdgcn_mfma_f32_16x16x32_bf16(a[k0], b, acc[c0], 0, 0, 0);
        }
    const float xi_m = 1.f - beta;
#pragma unroll
    for (int c0 = 0; c0 < 8; ++c0) {
        const int col = c0 * 16 + r;
#pragma unroll
        for (int v = 0; v < 4; ++v) {
            const int orow = row0 + kb * 4 + v;
            const size_t off = (size_t)orow * NHID + col;
            union { ushort_t u; __hip_bfloat16 b; } cv; cv.u = x[off];
            const float xi = __bfloat162float(cv.b);
            float val = xi_m * xi + beta * acc[c0][v];
            val = val > 0.f ? val : 0.f;
            x[off] = f2b(val);
        }
    }
}

// ---- fused layer-2 GEMM + output GEMM:
//  x2 = relu((1-beta)*x + beta*(x @ W));  out = x2 @ Wout + bout
//  x2 stays in LDS (per-wave swizzled tile); x never written back to global. ----
__global__ __launch_bounds__(256)
void layer2_out_gemm_kernel(const ushort_t* __restrict__ x, const ushort_t* __restrict__ Wt,
                            const ushort_t* __restrict__ WoT, const float* __restrict__ bias,
                            float beta, float* __restrict__ out) {
    __shared__ ushort_t xl[4][16 * 128];   // 4 waves x (16 rows x 128 cols) = 16 KB
    const int lane = threadIdx.x & 63, wave = threadIdx.x >> 6;
    const int row0 = blockIdx.x * 64 + wave * 16;
    const bool act = row0 < NODES;
    const int r = lane & 15, kb = lane >> 4;
    ushort_t* xw = &xl[wave][0];

    if (act) {
        const int row = row0 + r;
        bf16x8 a[4];
#pragma unroll
        for (int k0 = 0; k0 < 4; ++k0)
            a[k0] = *(const bf16x8*)(x + (size_t)row * NHID + k0 * 32 + kb * 8);
        f32x4 acc[8] = {};
#pragma unroll
        for (int k0 = 0; k0 < 4; ++k0)
#pragma unroll
            for (int c0 = 0; c0 < 8; ++c0) {
                const bf16x8 b = *(const bf16x8*)(Wt + (size_t)(c0 * 16 + r) * NHID + k0 * 32 + kb * 8);
                acc[c0] = __builtin_amdgcn_mfma_f32_16x16x32_bf16(a[k0], b, acc[c0], 0, 0, 0);
            }
        const float xi_m = 1.f - beta;
#pragma unroll
        for (int c0 = 0; c0 < 8; ++c0) {
            const int col = c0 * 16 + r;
#pragma unroll
            for (int v = 0; v < 4; ++v) {
                const int lrow = kb * 4 + v;
                const size_t off = (size_t)(row0 + lrow) * NHID + col;
                union { ushort_t u; __hip_bfloat16 b; } cv; cv.u = x[off];
                const float xi = __bfloat162float(cv.b);
                float val = xi_m * xi + beta * acc[c0][v];
                val = val > 0.f ? val : 0.f;
                const int byte = (lrow * 256 + col * 2) ^ ((lrow & 15) << 4);
                xw[byte >> 1] = f2b(val);
            }
        }
    }
    __syncthreads();
    if (!act) return;

    // phase 2: A-frags for this wave's 16 rows from swizzled LDS
    bf16x8 a2[4];
#pragma unroll
    for (int k0 = 0; k0 < 4; ++k0) {
        const int byte = (r * 256 + (k0 * 64 + kb * 16)) ^ (r << 4);
        a2[k0] = *(const bf16x8*)(xw + (byte >> 1));
    }
    f32x4 acc2[4];
#pragma unroll
    for (int c0 = 0; c0 < 4; ++c0) {
        const float bv = bias[c0 * 16 + r];
        acc2[c0] = (f32x4){bv, bv, bv, bv};
    }
#pragma unroll
    for (int k0 = 0; k0 < 4; ++k0)
#pragma unroll
        for (int c0 = 0; c0 < 4; ++c0) {
            const bf16x8 b = *(const bf16x8*)(WoT + (size_t)(c0 * 16 + r) * NHID + k0 * 32 + kb * 8);
            acc2[c0] = __builtin_amdgcn_mfma_f32_16x16x32_bf16(a2[k0], b, acc2[c0], 0, 0, 0);
        }
#pragma unroll
    for (int c0 = 0; c0 < 4; ++c0) {
        const int col = c0 * 16 + r;
#pragma unroll
        for (int v = 0; v < 4; ++v) {
            const int orow = row0 + kb * 4 + v;
            out[(size_t)orow * FOUT + col] = acc2[c0][v];
        }
    }
}

extern "C" void kernel_launch(void* const* d_in, const int* in_sizes, int n_in,
                              void* d_out, int out_size, void* d_ws, size_t ws_size,
                              hipStream_t stream) {
    const float* x_in  = (const float*)d_in[0];
    const float* W0    = (const float*)d_in[1];
    const float* b0    = (const float*)d_in[2];
    const float* Ws    = (const float*)d_in[3];
    const float* Wout  = (const float*)d_in[4];
    const float* bout  = (const float*)d_in[5];
    const int* vertex  = (const int*)d_in[6];
    const int* edges   = (const int*)d_in[7];

    ushort_t* Xe   = (ushort_t*)d_ws;                       // EDGES*NHID bf16 (2.56 MB)
    ushort_t* x    = Xe + (size_t)EDGES * NHID;             // NODES*NHID bf16
    ushort_t* x0   = x  + (size_t)NODES * NHID;             // NODES*NHID bf16
    ushort_t* Wt0  = x0 + (size_t)NODES * NHID;             // 128*128
    ushort_t* WsT  = Wt0 + 128 * 128;                       // 2*128*128
    ushort_t* WoutT= WsT + 2 * 128 * 128;                   // 64*128
    int* cnt_e = (int*)(WoutT + 64 * 128);                  // EDGES
    int* cnt_v = cnt_e + EDGES;                             // NODES
    int* rp_e  = cnt_v + NODES;                             // EDGES+1
    int* rp_v  = rp_e + EDGES + 1;                          // NODES+1
    int* rank_e= rp_v + NODES + 3;                          // NNZ (pad keeps 16B alignment)
    int* rank_v= rank_e + NNZ;                              // NNZ
    int* col_e = rank_v + NNZ;                              // NNZ
    int* col_v = col_e + NNZ;                               // NNZ

    float* out    = (float*)d_out;                          // [NODES, FOUT]
    float* out_xe = out + (size_t)NODES * FOUT;             // [EDGES, NHID]

    hipMemsetAsync(cnt_e, 0, (size_t)(EDGES + NODES) * sizeof(int), stream);

    // K1: edge histogram + weight conversion
    hist_e_wconv_kernel<<<HIST_BLOCKS + WCONV_BLOCKS, 256, 0, stream>>>(
        edges, cnt_e, rank_e, W0, Ws, Wout, Wt0, WsT, WoutT);
    // K2: scan edge counts
    scan_e_kernel<<<1, 1024, 0, stream>>>(cnt_e, rp_e);
    // K3: fill edge-CSR + vertex histogram + input GEMM
    fille_histv_gemm_kernel<<<FILL_BLOCKS + GEMM_BLOCKS, 256, 0, stream>>>(
        vertex, edges, rank_e, rp_e, col_e, cnt_v, rank_v, x_in, Wt0, b0, x, x0);
    // K4: scan vertex counts
    scan_v_kernel<<<1, 1024, 0, stream>>>(cnt_v, rp_v);
    // K5: fill vertex-CSR + layer-1 edge gather
    fillv_edgegather_kernel<<<FILL_BLOCKS + EDGE_BLOCKS, 256, 0, stream>>>(
        vertex, edges, rank_v, rp_v, col_v, x, rp_e, col_e, Xe);

    const float betas[2] = {logf(1.5f), logf(1.25f)};  // log(0.5/(i+1)+1)

    // layer 1 (edge gather already done in K5)
    node_gather_post_kernel<<<NODE_BLOCKS, 256, 0, stream>>>(Xe, rp_v, col_v, x0, x);
    layer_gemm_kernel<<<GEMM_BLOCKS, 256, 0, stream>>>(x, WsT, betas[0]);

    // layer 2
    edge_gather_kernel<<<EDGE_BLOCKS, 256, 0, stream>>>(x, rp_e, col_e, Xe, out_xe);
    node_gather_post_kernel<<<NODE_BLOCKS, 256, 0, stream>>>(Xe, rp_v, col_v, x0, x);
    layer2_out_gemm_kernel<<<GEMM_BLOCKS, 256, 0, stream>>>(
        x, WsT + (size_t)NHID * NHID, WoutT, bout, betas[1], out);
}

// Round 10
// 272.449 us; speedup vs baseline: 1.7063x; 1.1529x over previous
//
#include <hip/hip_runtime.h>
#include <hip/hip_bf16.h>
#include <math.h>

#define NODES 50000
#define EDGES 10000
#define NNZ   800000
#define FIN   128
#define NHID  128
#define FOUT  64

#define HIST_BLOCKS  (NNZ / 256)          // 3125
#define WCONV_BLOCKS 128
#define FILL_BLOCKS  (NNZ / 256)          // 3125
#define GEMM_BLOCKS  ((NODES + 63) / 64)  // 782
#define EDGE_BLOCKS  (EDGES * 64 / 256)   // 2500
#define NF_BLOCKS    (NODES / 16)         // 3125 (50000 = 16*3125 exactly)

typedef __attribute__((ext_vector_type(8))) short bf16x8;
typedef __attribute__((ext_vector_type(4))) float f32x4;
typedef unsigned short ushort_t;

__device__ __forceinline__ ushort_t f2b(float f) {
    __hip_bfloat16 h = __float2bfloat16(f);
    return *reinterpret_cast<ushort_t*>(&h);
}
__device__ __forceinline__ float u2f(unsigned u) {
    union { unsigned u; float f; } c; c.u = u; return c.f;
}
__device__ __forceinline__ float us2f(ushort_t u) { return u2f((unsigned)u << 16); }
__device__ __forceinline__ unsigned pk2(float lo, float hi) {
    return (unsigned)f2b(lo) | ((unsigned)f2b(hi) << 16);
}

// ---- K1: histogram+rank of EDGE keys | weight transpose/convert ----
__global__ __launch_bounds__(256)
void hist_e_wconv_kernel(const int* __restrict__ edges,
                         int* __restrict__ cnt_e, int* __restrict__ rank_e,
                         const float* __restrict__ W0, const float* __restrict__ Ws,
                         const float* __restrict__ Wout,
                         ushort_t* __restrict__ Wt0, ushort_t* __restrict__ WsT,
                         ushort_t* __restrict__ WoutT) {
    if (blockIdx.x < HIST_BLOCKS) {
        const int i = blockIdx.x * 256 + threadIdx.x;
        rank_e[i] = atomicAdd(&cnt_e[edges[i]], 1);
    } else {
        const int i = (blockIdx.x - HIST_BLOCKS) * 256 + threadIdx.x;
        if (i < 128 * 128) { int c = i >> 7, k = i & 127; Wt0[c * 128 + k] = f2b(W0[k * 128 + c]); }
        if (i < 2 * 128 * 128) {
            int l = i >> 14, r = i & 16383, c = r >> 7, k = r & 127;
            WsT[l * 16384 + c * 128 + k] = f2b(Ws[l * 16384 + k * 128 + c]);
        }
        if (i < 64 * 128) { int c = i >> 7, k = i & 127; WoutT[c * 128 + k] = f2b(Wout[k * 64 + c]); }
    }
}

// ---- exclusive scan, 8 items/thread, single 1024-thread block ----
__device__ __forceinline__ void scan_impl(const int* __restrict__ cnt, int* __restrict__ rp,
                                          const int n) {
    __shared__ int wsum[16];
    __shared__ int carry_sh;
    const int t = threadIdx.x, lane = t & 63, w = t >> 6;
    if (t == 0) carry_sh = 0;
    __syncthreads();
    for (int base = 0; base < n; base += 8192) {
        const int idx = base + t * 8;
        int v[8];
        if (idx + 8 <= n) {
            const int4 a = *(const int4*)(cnt + idx);
            const int4 b = *(const int4*)(cnt + idx + 4);
            v[0] = a.x; v[1] = a.y; v[2] = a.z; v[3] = a.w;
            v[4] = b.x; v[5] = b.y; v[6] = b.z; v[7] = b.w;
        } else {
#pragma unroll
            for (int j = 0; j < 8; ++j) v[j] = (idx + j < n) ? cnt[idx + j] : 0;
        }
        int sum8 = 0;
#pragma unroll
        for (int j = 0; j < 8; ++j) sum8 += v[j];
        int x = sum8;
#pragma unroll
        for (int o = 1; o < 64; o <<= 1) {
            int y = __shfl_up(x, o);
            if (lane >= o) x += y;
        }
        if (lane == 63) wsum[w] = x;
        __syncthreads();
        if (t < 16) {
            int s = wsum[t];
#pragma unroll
            for (int o = 1; o < 16; o <<= 1) {
                int y = __shfl_up(s, o);
                if (t >= o) s += y;
            }
            wsum[t] = s;
        }
        __syncthreads();
        const int carry = carry_sh;
        int pre = carry + (x - sum8) + (w ? wsum[w - 1] : 0);
        if (idx < n) {
#pragma unroll
            for (int j = 0; j < 8; ++j)
                if (idx + j < n) { rp[idx + j] = pre; pre += v[j]; }
        }
        __syncthreads();
        if (t == 1023) carry_sh = carry + wsum[15];
        __syncthreads();
    }
    if (t == 0) rp[n] = carry_sh;
}

__global__ __launch_bounds__(1024)
void scan_e_kernel(const int* __restrict__ cnt_e, int* __restrict__ rp_e) {
    scan_impl(cnt_e, rp_e, EDGES);
}
__global__ __launch_bounds__(1024)
void scan_v_kernel(const int* __restrict__ cnt_v, int* __restrict__ rp_v) {
    scan_impl(cnt_v, rp_v, NODES);
}

// ---- K3: fill edge-CSR + histogram vertex keys | input GEMM (MFMA), x0 only ----
__global__ __launch_bounds__(256)
void fille_histv_gemm_kernel(const int* __restrict__ vertex, const int* __restrict__ edges,
                             const int* __restrict__ rank_e, const int* __restrict__ rp_e,
                             int* __restrict__ col_e,
                             int* __restrict__ cnt_v, int* __restrict__ rank_v,
                             const float* __restrict__ X, const ushort_t* __restrict__ Wt,
                             const float* __restrict__ bias,
                             ushort_t* __restrict__ x0) {
    if (blockIdx.x < FILL_BLOCKS) {
        const int i = blockIdx.x * 256 + threadIdx.x;
        const int e = edges[i], v = vertex[i];
        col_e[rp_e[e] + rank_e[i]] = v;
        rank_v[i] = atomicAdd(&cnt_v[v], 1);
        return;
    }
    const int lane = threadIdx.x & 63, wave = threadIdx.x >> 6;
    const int row0 = (blockIdx.x - FILL_BLOCKS) * 64 + wave * 16;
    if (row0 >= NODES) return;
    const int r = lane & 15, kb = lane >> 4;
    const int row = row0 + r;
    bf16x8 a[4];
#pragma unroll
    for (int k0 = 0; k0 < 4; ++k0) {
        const float* p = X + (size_t)row * FIN + k0 * 32 + kb * 8;
        const float4 lo = *(const float4*)p;
        const float4 hi = *(const float4*)(p + 4);
        bf16x8 t;
        t[0] = f2b(lo.x); t[1] = f2b(lo.y); t[2] = f2b(lo.z); t[3] = f2b(lo.w);
        t[4] = f2b(hi.x); t[5] = f2b(hi.y); t[6] = f2b(hi.z); t[7] = f2b(hi.w);
        a[k0] = t;
    }
    f32x4 acc[8];
#pragma unroll
    for (int c0 = 0; c0 < 8; ++c0) {
        const float bv = bias[c0 * 16 + r];
        acc[c0] = (f32x4){bv, bv, bv, bv};
    }
#pragma unroll
    for (int k0 = 0; k0 < 4; ++k0)
#pragma unroll
        for (int c0 = 0; c0 < 8; ++c0) {
            const bf16x8 b = *(const bf16x8*)(Wt + (size_t)(c0 * 16 + r) * FIN + k0 * 32 + kb * 8);
            acc[c0] = __builtin_amdgcn_mfma_f32_16x16x32_bf16(a[k0], b, acc[c0], 0, 0, 0);
        }
#pragma unroll
    for (int c0 = 0; c0 < 8; ++c0) {
        const int col = c0 * 16 + r;
#pragma unroll
        for (int v = 0; v < 4; ++v) {
            const int orow = row0 + kb * 4 + v;
            float val = acc[c0][v];
            val = val > 0.f ? val : 0.f;
            x0[(size_t)orow * NHID + col] = f2b(val);
        }
    }
}

// ---- edge gather body: 16 lanes/row, uint4 loads, 4 rows in flight per wave ----
__device__ __forceinline__ void edge_gather_body(const int e,
                                                 const ushort_t* __restrict__ x,
                                                 const int* __restrict__ rp,
                                                 const int* __restrict__ ci,
                                                 ushort_t* __restrict__ Xe,
                                                 float* __restrict__ out_xe) {
    const int lane = threadIdx.x & 63;
    const int sub = lane >> 4, lr = lane & 15;
    const int beg = rp[e], end = rp[e + 1];
    float a[8] = {};
    for (int base = beg; base < end; base += 64) {
        const int m = min(64, end - base);
        const int idx_l = (lane < m) ? ci[base + lane] : 0;
        const int steps = (m + 3) >> 2;
#pragma unroll 4
        for (int j = 0; j < steps; ++j) {
            const int slot = j * 4 + sub;
            const int src = __shfl(idx_l, slot);
            if (slot < m) {
                const uint4 d = *(const uint4*)(x + (size_t)src * NHID + lr * 8);
                a[0] += u2f(d.x << 16); a[1] += u2f(d.x & 0xffff0000u);
                a[2] += u2f(d.y << 16); a[3] += u2f(d.y & 0xffff0000u);
                a[4] += u2f(d.z << 16); a[5] += u2f(d.z & 0xffff0000u);
                a[6] += u2f(d.w << 16); a[7] += u2f(d.w & 0xffff0000u);
            }
        }
    }
#pragma unroll
    for (int k = 0; k < 8; ++k) {
        a[k] += __shfl_xor(a[k], 16);
        a[k] += __shfl_xor(a[k], 32);
    }
    const float inv = 1.f / (float)max(end - beg, 1);
    if (sub == 0) {
        float vv[8];
#pragma unroll
        for (int k = 0; k < 8; ++k) vv[k] = a[k] * inv;
        uint4 o;
        o.x = pk2(vv[0], vv[1]); o.y = pk2(vv[2], vv[3]);
        o.z = pk2(vv[4], vv[5]); o.w = pk2(vv[6], vv[7]);
        *(uint4*)(Xe + (size_t)e * NHID + lr * 8) = o;
        if (out_xe) {
            const float4 f0 = {vv[0], vv[1], vv[2], vv[3]};
            const float4 f1 = {vv[4], vv[5], vv[6], vv[7]};
            *(float4*)(out_xe + (size_t)e * NHID + lr * 8) = f0;
            *(float4*)(out_xe + (size_t)e * NHID + lr * 8 + 4) = f1;
        }
    }
}

// ---- K5: fill vertex-CSR | edge gather (layer 1, src = x0) ----
__global__ __launch_bounds__(256)
void fillv_edgegather_kernel(const int* __restrict__ vertex, const int* __restrict__ edges,
                             const int* __restrict__ rank_v, const int* __restrict__ rp_v,
                             int* __restrict__ col_v,
                             const ushort_t* __restrict__ x0, const int* __restrict__ rp_e,
                             const int* __restrict__ col_e, ushort_t* __restrict__ Xe) {
    if (blockIdx.x < FILL_BLOCKS) {
        const int i = blockIdx.x * 256 + threadIdx.x;
        col_v[rp_v[vertex[i]] + rank_v[i]] = edges[i];
        return;
    }
    const int e = ((blockIdx.x - FILL_BLOCKS) * 256 + (int)threadIdx.x) >> 6;
    if (e >= EDGES) return;
    edge_gather_body(e, x0, rp_e, col_e, Xe, (float*)nullptr);
}

// ---- edge gather standalone (layer 2, with f32 output copy) ----
__global__ __launch_bounds__(256)
void edge_gather_kernel(const ushort_t* __restrict__ x, const int* __restrict__ rp,
                        const int* __restrict__ ci, ushort_t* __restrict__ Xe,
                        float* __restrict__ out_xe) {
    const int e = (blockIdx.x * 256 + (int)threadIdx.x) >> 6;
    if (e >= EDGES) return;
    edge_gather_body(e, x, rp, ci, Xe, out_xe);
}

// ---- node phase 1: gather + mean + L2-normalize + residual -> Xi row in LDS ----
// block = 256 threads = 16 subgroups of 16 lanes; subgroup s of wave w owns row w*4+s.
// xl layout: [16 rows][136 ushorts] (272 B row stride, 16B-aligned).
__device__ __forceinline__ void node_phase1(const ushort_t* __restrict__ Xe,
                                            const int* __restrict__ rp,
                                            const int* __restrict__ ci,
                                            const ushort_t* __restrict__ x0,
                                            const int vbase,
                                            ushort_t* __restrict__ xl) {
    const int lane = threadIdx.x & 63, wave = threadIdx.x >> 6;
    const int sub = lane >> 4, lr = lane & 15;
    const int row = wave * 4 + sub;
    const int v = vbase + row;
    const int beg = rp[v], end = rp[v + 1];
    const int sbase = lane & 48;   // subgroup's base lane
    float a[8] = {};
    for (int base = beg; base < end; base += 16) {
        const int m = min(16, end - base);
        const int idx_l = (lr < m) ? ci[base + lr] : 0;
#pragma unroll 4
        for (int j = 0; j < m; ++j) {
            const int src = __shfl(idx_l, sbase + j);
            const uint4 d = *(const uint4*)(Xe + (size_t)src * NHID + lr * 8);
            a[0] += u2f(d.x << 16); a[1] += u2f(d.x & 0xffff0000u);
            a[2] += u2f(d.y << 16); a[3] += u2f(d.y & 0xffff0000u);
            a[4] += u2f(d.z << 16); a[5] += u2f(d.z & 0xffff0000u);
            a[6] += u2f(d.w << 16); a[7] += u2f(d.w & 0xffff0000u);
        }
    }
    const float inv = 1.f / (float)max(end - beg, 1);
    float mk[8], s = 0.f;
#pragma unroll
    for (int k = 0; k < 8; ++k) { mk[k] = a[k] * inv; s += mk[k] * mk[k]; }
    s += __shfl_xor(s, 1); s += __shfl_xor(s, 2);
    s += __shfl_xor(s, 4); s += __shfl_xor(s, 8);
    const float norm = sqrtf(s);
    const float scale = norm > 0.f ? 1.f / fmaxf(norm, 1e-30f) : 0.f;
    const uint4 u0 = *(const uint4*)(x0 + (size_t)v * NHID + lr * 8);
    float xv[8];
    xv[0] = u2f(u0.x << 16); xv[1] = u2f(u0.x & 0xffff0000u);
    xv[2] = u2f(u0.y << 16); xv[3] = u2f(u0.y & 0xffff0000u);
    xv[4] = u2f(u0.z << 16); xv[5] = u2f(u0.z & 0xffff0000u);
    xv[6] = u2f(u0.w << 16); xv[7] = u2f(u0.w & 0xffff0000u);
    float o[8];
#pragma unroll
    for (int k = 0; k < 8; ++k) o[k] = 0.9f * mk[k] * scale + 0.1f * xv[k];
    uint4 ou;
    ou.x = pk2(o[0], o[1]); ou.y = pk2(o[2], o[3]);
    ou.z = pk2(o[4], o[5]); ou.w = pk2(o[6], o[7]);
    *(uint4*)(xl + row * 136 + lr * 8) = ou;
}

// ---- K6: node gather+post fused with layer-1 GEMM: x = relu((1-b)Xi + b(Xi@W)) ----
__global__ __launch_bounds__(256)
void node_l1_kernel(const ushort_t* __restrict__ Xe, const int* __restrict__ rp,
                    const int* __restrict__ ci, const ushort_t* __restrict__ x0,
                    const ushort_t* __restrict__ Wt, float beta,
                    ushort_t* __restrict__ xout) {
    __shared__ ushort_t xl[16 * 136];
    const int vbase = blockIdx.x * 16;
    node_phase1(Xe, rp, ci, x0, vbase, xl);
    __syncthreads();
    const int lane = threadIdx.x & 63, wave = threadIdx.x >> 6;
    const int r = lane & 15, kb = lane >> 4;
    bf16x8 a2[4];
#pragma unroll
    for (int k0 = 0; k0 < 4; ++k0)
        a2[k0] = *(const bf16x8*)(xl + r * 136 + k0 * 32 + kb * 8);
    f32x4 acc[2] = {};
#pragma unroll
    for (int k0 = 0; k0 < 4; ++k0)
#pragma unroll
        for (int cc = 0; cc < 2; ++cc) {
            const int c0 = wave * 2 + cc;
            const bf16x8 b = *(const bf16x8*)(Wt + (size_t)(c0 * 16 + r) * NHID + k0 * 32 + kb * 8);
            acc[cc] = __builtin_amdgcn_mfma_f32_16x16x32_bf16(a2[k0], b, acc[cc], 0, 0, 0);
        }
    const float xim = 1.f - beta;
#pragma unroll
    for (int cc = 0; cc < 2; ++cc) {
        const int col = (wave * 2 + cc) * 16 + r;
#pragma unroll
        for (int v = 0; v < 4; ++v) {
            const int row = kb * 4 + v;
            const float xi = us2f(xl[row * 136 + col]);
            float val = xim * xi + beta * acc[cc][v];
            val = val > 0.f ? val : 0.f;
            xout[(size_t)(vbase + row) * NHID + col] = f2b(val);
        }
    }
}

// ---- K8: node gather+post fused with layer-2 GEMM AND output GEMM ----
__global__ __launch_bounds__(256)
void node_l2_out_kernel(const ushort_t* __restrict__ Xe, const int* __restrict__ rp,
                        const int* __restrict__ ci, const ushort_t* __restrict__ x0,
                        const ushort_t* __restrict__ Wt, const ushort_t* __restrict__ WoT,
                        const float* __restrict__ bias, float beta,
                        float* __restrict__ out) {
    __shared__ ushort_t xl[16 * 136];
    __shared__ ushort_t x2[16 * 136];
    const int vbase = blockIdx.x * 16;
    node_phase1(Xe, rp, ci, x0, vbase, xl);
    __syncthreads();
    const int lane = threadIdx.x & 63, wave = threadIdx.x >> 6;
    const int r = lane & 15, kb = lane >> 4;
    {
        bf16x8 a2[4];
#pragma unroll
        for (int k0 = 0; k0 < 4; ++k0)
            a2[k0] = *(const bf16x8*)(xl + r * 136 + k0 * 32 + kb * 8);
        f32x4 acc[2] = {};
#pragma unroll
        for (int k0 = 0; k0 < 4; ++k0)
#pragma unroll
            for (int cc = 0; cc < 2; ++cc) {
                const int c0 = wave * 2 + cc;
                const bf16x8 b = *(const bf16x8*)(Wt + (size_t)(c0 * 16 + r) * NHID + k0 * 32 + kb * 8);
                acc[cc] = __builtin_amdgcn_mfma_f32_16x16x32_bf16(a2[k0], b, acc[cc], 0, 0, 0);
            }
        const float xim = 1.f - beta;
#pragma unroll
        for (int cc = 0; cc < 2; ++cc) {
            const int col = (wave * 2 + cc) * 16 + r;
#pragma unroll
            for (int v = 0; v < 4; ++v) {
                const int row = kb * 4 + v;
                const float xi = us2f(xl[row * 136 + col]);
                float val = xim * xi + beta * acc[cc][v];
                val = val > 0.f ? val : 0.f;
                x2[row * 136 + col] = f2b(val);
            }
        }
    }
    __syncthreads();
    // output GEMM: wave w computes columns w*16 .. w*16+15
    bf16x8 a3[4];
#pragma unroll
    for (int k0 = 0; k0 < 4; ++k0)
        a3[k0] = *(const bf16x8*)(x2 + r * 136 + k0 * 32 + kb * 8);
    const float bv = bias[wave * 16 + r];
    f32x4 facc = (f32x4){bv, bv, bv, bv};
#pragma unroll
    for (int k0 = 0; k0 < 4; ++k0) {
        const bf16x8 b = *(const bf16x8*)(WoT + (size_t)(wave * 16 + r) * NHID + k0 * 32 + kb * 8);
        facc = __builtin_amdgcn_mfma_f32_16x16x32_bf16(a3[k0], b, facc, 0, 0, 0);
    }
#pragma unroll
    for (int v = 0; v < 4; ++v) {
        const int row = kb * 4 + v;
        out[(size_t)(vbase + row) * FOUT + wave * 16 + r] = facc[v];
    }
}

extern "C" void kernel_launch(void* const* d_in, const int* in_sizes, int n_in,
                              void* d_out, int out_size, void* d_ws, size_t ws_size,
                              hipStream_t stream) {
    const float* x_in  = (const float*)d_in[0];
    const float* W0    = (const float*)d_in[1];
    const float* b0    = (const float*)d_in[2];
    const float* Ws    = (const float*)d_in[3];
    const float* Wout  = (const float*)d_in[4];
    const float* bout  = (const float*)d_in[5];
    const int* vertex  = (const int*)d_in[6];
    const int* edges   = (const int*)d_in[7];

    ushort_t* Xe   = (ushort_t*)d_ws;                       // EDGES*NHID bf16 (2.56 MB)
    ushort_t* x    = Xe + (size_t)EDGES * NHID;             // NODES*NHID bf16
    ushort_t* x0   = x  + (size_t)NODES * NHID;             // NODES*NHID bf16
    ushort_t* Wt0  = x0 + (size_t)NODES * NHID;             // 128*128
    ushort_t* WsT  = Wt0 + 128 * 128;                       // 2*128*128
    ushort_t* WoutT= WsT + 2 * 128 * 128;                   // 64*128
    int* cnt_e = (int*)(WoutT + 64 * 128);                  // EDGES
    int* cnt_v = cnt_e + EDGES;                             // NODES
    int* rp_e  = cnt_v + NODES;                             // EDGES+1
    int* rp_v  = rp_e + EDGES + 1;                          // NODES+1
    int* rank_e= rp_v + NODES + 3;                          // NNZ (pad keeps 16B alignment)
    int* rank_v= rank_e + NNZ;                              // NNZ
    int* col_e = rank_v + NNZ;                              // NNZ
    int* col_v = col_e + NNZ;                               // NNZ

    float* out    = (float*)d_out;                          // [NODES, FOUT]
    float* out_xe = out + (size_t)NODES * FOUT;             // [EDGES, NHID]

    hipMemsetAsync(cnt_e, 0, (size_t)(EDGES + NODES) * sizeof(int), stream);

    // K1: edge histogram + weight conversion
    hist_e_wconv_kernel<<<HIST_BLOCKS + WCONV_BLOCKS, 256, 0, stream>>>(
        edges, cnt_e, rank_e, W0, Ws, Wout, Wt0, WsT, WoutT);
    // K2: scan edge counts
    scan_e_kernel<<<1, 1024, 0, stream>>>(cnt_e, rp_e);
    // K3: fill edge-CSR + vertex histogram + input GEMM (writes x0 only)
    fille_histv_gemm_kernel<<<FILL_BLOCKS + GEMM_BLOCKS, 256, 0, stream>>>(
        vertex, edges, rank_e, rp_e, col_e, cnt_v, rank_v, x_in, Wt0, b0, x0);
    // K4: scan vertex counts
    scan_v_kernel<<<1, 1024, 0, stream>>>(cnt_v, rp_v);
    // K5: fill vertex-CSR + layer-1 edge gather (src = x0)
    fillv_edgegather_kernel<<<FILL_BLOCKS + EDGE_BLOCKS, 256, 0, stream>>>(
        vertex, edges, rank_v, rp_v, col_v, x0, rp_e, col_e, Xe);

    const float betas[2] = {logf(1.5f), logf(1.25f)};  // log(0.5/(i+1)+1)

    // K6: layer-1 node gather + post + layer GEMM -> x
    node_l1_kernel<<<NF_BLOCKS, 256, 0, stream>>>(Xe, rp_v, col_v, x0, WsT, betas[0], x);
    // K7: layer-2 edge gather (+ f32 copy to output 1)
    edge_gather_kernel<<<EDGE_BLOCKS, 256, 0, stream>>>(x, rp_e, col_e, Xe, out_xe);
    // K8: layer-2 node gather + post + layer GEMM + output GEMM -> out
    node_l2_out_kernel<<<NF_BLOCKS, 256, 0, stream>>>(
        Xe, rp_v, col_v, x0, WsT + (size_t)NHID * NHID, WoutT, bout, betas[1], out);
}

// Round 11
// 213.406 us; speedup vs baseline: 2.1784x; 1.2767x over previous
//
#include <hip/hip_runtime.h>
#include <hip/hip_bf16.h>
#include <math.h>

#define NODES 50000
#define EDGES 10000
#define NNZ   800000
#define FIN   128
#define NHID  128
#define FOUT  64

#define NHB    128                 // hist/fill blocks per side
#define SLICE  (NNZ / NHB)         // 6250 entries per block slice
#define VHALF  25000               // vertex keys per half
#define VWORDS (VHALF / 2)         // 12500 packed words per half

#define WCONV_BLOCKS 128
#define GEMM_BLOCKS  ((NODES + 63) / 64)  // 782
#define EDGE_BLOCKS  (EDGES * 64 / 256)   // 2500
#define NF_BLOCKS    (NODES / 16)         // 3125

typedef __attribute__((ext_vector_type(8))) short bf16x8;
typedef __attribute__((ext_vector_type(4))) float f32x4;
typedef unsigned short ushort_t;
typedef unsigned int uint_t;

__device__ __forceinline__ ushort_t f2b(float f) {
    __hip_bfloat16 h = __float2bfloat16(f);
    return *reinterpret_cast<ushort_t*>(&h);
}
__device__ __forceinline__ float u2f(unsigned u) {
    union { unsigned u; float f; } c; c.u = u; return c.f;
}
__device__ __forceinline__ float us2f(ushort_t u) { return u2f((unsigned)u << 16); }
__device__ __forceinline__ unsigned pk2(float lo, float hi) {
    return (unsigned)f2b(lo) | ((unsigned)f2b(hi) << 16);
}

// ---- K1: LDS histograms (edge keys | vertex keys in 2 packed halves) | wconv ----
__global__ __launch_bounds__(256)
void hist_wconv_kernel(const int* __restrict__ vertex, const int* __restrict__ edges,
                       uint_t* __restrict__ cbe, uint_t* __restrict__ cbv,
                       const float* __restrict__ W0, const float* __restrict__ Ws,
                       const float* __restrict__ Wout,
                       ushort_t* __restrict__ Wt0, ushort_t* __restrict__ WsT,
                       ushort_t* __restrict__ WoutT) {
    __shared__ uint_t lds_u[VWORDS];   // 50 KB, reused by both hist branches
    const int t = threadIdx.x;
    if (blockIdx.x < NHB) {                      // ---- edge histogram ----
        const int b = blockIdx.x;
        for (int k = t; k < EDGES; k += 256) lds_u[k] = 0;
        __syncthreads();
        const int base = b * SLICE;
        for (int i = base + t; i < base + SLICE; i += 256)
            atomicAdd(&lds_u[edges[i]], 1u);
        __syncthreads();
        for (int k = t; k < EDGES; k += 256) cbe[b * EDGES + k] = lds_u[k];
    } else if (blockIdx.x < NHB + 2 * NHB) {     // ---- vertex histogram (2 halves) ----
        const int hb = blockIdx.x - NHB, h = hb >> 7, bs = hb & 127;
        for (int w = t; w < VWORDS; w += 256) lds_u[w] = 0;
        __syncthreads();
        const int base = bs * SLICE, voff = h * VHALF;
        for (int i = base + t; i < base + SLICE; i += 256) {
            const int vk = vertex[i] - voff;
            if ((unsigned)vk < (unsigned)VHALF)
                atomicAdd(&lds_u[vk >> 1], 1u << ((vk & 1) * 16));
        }
        __syncthreads();
        for (int w = t; w < VWORDS; w += 256) cbv[hb * VWORDS + w] = lds_u[w];
    } else {                                     // ---- weight transpose/convert ----
        const int i = (blockIdx.x - 3 * NHB) * 256 + t;
        if (i < 128 * 128) { int c = i >> 7, k = i & 127; Wt0[c * 128 + k] = f2b(W0[k * 128 + c]); }
        if (i < 2 * 128 * 128) {
            int l = i >> 14, r = i & 16383, c = r >> 7, k = r & 127;
            WsT[l * 16384 + c * 128 + k] = f2b(Ws[l * 16384 + k * 128 + c]);
        }
        if (i < 64 * 128) { int c = i >> 7, k = i & 127; WoutT[c * 128 + k] = f2b(Wout[k * 64 + c]); }
    }
}

// ---- K2a: per-key exclusive scan over block counts (columns of cbe / cbv) ----
__global__ __launch_bounds__(256)
void colscan_kernel(uint_t* __restrict__ cbe, uint_t* __restrict__ cbv,
                    int* __restrict__ cnt_e, int* __restrict__ cnt_v) {
    const int flat = blockIdx.x * 256 + threadIdx.x;
    if (flat < EDGES) {
        uint_t sum = 0;
        for (int b = 0; b < NHB; ++b) {
            uint_t* p = &cbe[b * EDGES + flat];
            const uint_t tv = *p; *p = sum; sum += tv;
        }
        cnt_e[flat] = (int)sum;
    } else if (flat < EDGES + 2 * VWORDS) {
        const int idx = flat - EDGES, h = idx / VWORDS, w = idx % VWORDS;
        uint_t s0 = 0, s1 = 0;
        for (int bs = 0; bs < NHB; ++bs) {
            uint_t* p = &cbv[(h * NHB + bs) * VWORDS + w];
            const uint_t u = *p; *p = s0 | (s1 << 16);
            s0 += u & 0xffffu; s1 += u >> 16;
        }
        cnt_v[h * VHALF + 2 * w]     = (int)s0;
        cnt_v[h * VHALF + 2 * w + 1] = (int)s1;
    }
}

// ---- exclusive scan, 8 items/thread, single 1024-thread block ----
__device__ __forceinline__ void scan_impl(const int* __restrict__ cnt, int* __restrict__ rp,
                                          const int n) {
    __shared__ int wsum[16];
    __shared__ int carry_sh;
    const int t = threadIdx.x, lane = t & 63, w = t >> 6;
    if (t == 0) carry_sh = 0;
    __syncthreads();
    for (int base = 0; base < n; base += 8192) {
        const int idx = base + t * 8;
        int v[8];
        if (idx + 8 <= n) {
            const int4 a = *(const int4*)(cnt + idx);
            const int4 b = *(const int4*)(cnt + idx + 4);
            v[0] = a.x; v[1] = a.y; v[2] = a.z; v[3] = a.w;
            v[4] = b.x; v[5] = b.y; v[6] = b.z; v[7] = b.w;
        } else {
#pragma unroll
            for (int j = 0; j < 8; ++j) v[j] = (idx + j < n) ? cnt[idx + j] : 0;
        }
        int sum8 = 0;
#pragma unroll
        for (int j = 0; j < 8; ++j) sum8 += v[j];
        int x = sum8;
#pragma unroll
        for (int o = 1; o < 64; o <<= 1) {
            int y = __shfl_up(x, o);
            if (lane >= o) x += y;
        }
        if (lane == 63) wsum[w] = x;
        __syncthreads();
        if (t < 16) {
            int s = wsum[t];
#pragma unroll
            for (int o = 1; o < 16; o <<= 1) {
                int y = __shfl_up(s, o);
                if (t >= o) s += y;
            }
            wsum[t] = s;
        }
        __syncthreads();
        const int carry = carry_sh;
        int pre = carry + (x - sum8) + (w ? wsum[w - 1] : 0);
        if (idx < n) {
#pragma unroll
            for (int j = 0; j < 8; ++j)
                if (idx + j < n) { rp[idx + j] = pre; pre += v[j]; }
        }
        __syncthreads();
        if (t == 1023) carry_sh = carry + wsum[15];
        __syncthreads();
    }
    if (t == 0) rp[n] = carry_sh;
}

// ---- K2b: both rp scans in one launch ----
__global__ __launch_bounds__(1024)
void scan2_kernel(const int* __restrict__ cnt_e, int* __restrict__ rp_e,
                  const int* __restrict__ cnt_v, int* __restrict__ rp_v) {
    if (blockIdx.x == 0) scan_impl(cnt_e, rp_e, EDGES);
    else                 scan_impl(cnt_v, rp_v, NODES);
}

// ---- K3: fill edge-CSR + fill vertex-CSR (LDS cursors) | input GEMM (MFMA) ----
__global__ __launch_bounds__(256)
void fill_gemm_kernel(const int* __restrict__ vertex, const int* __restrict__ edges,
                      const uint_t* __restrict__ cbe, const uint_t* __restrict__ cbv,
                      const int* __restrict__ rp_e, const int* __restrict__ rp_v,
                      int* __restrict__ col_e, int* __restrict__ col_v,
                      const float* __restrict__ X, const ushort_t* __restrict__ Wt,
                      const float* __restrict__ bias, ushort_t* __restrict__ x0) {
    __shared__ uint_t lds_u[VWORDS];
    const int t = threadIdx.x;
    if (blockIdx.x < NHB) {                      // ---- fill edge-CSR ----
        const int b = blockIdx.x;
        for (int k = t; k < EDGES; k += 256)
            lds_u[k] = (uint_t)rp_e[k] + cbe[b * EDGES + k];
        __syncthreads();
        const int base = b * SLICE;
        for (int i = base + t; i < base + SLICE; i += 256) {
            const int e = edges[i], v = vertex[i];
            const uint_t pos = atomicAdd(&lds_u[e], 1u);
            col_e[pos] = v;
        }
        return;
    }
    if (blockIdx.x < 3 * NHB) {                  // ---- fill vertex-CSR (2 halves) ----
        const int fb = blockIdx.x - NHB, h = fb >> 7, bs = fb & 127;
        for (int w = t; w < VWORDS; w += 256) lds_u[w] = cbv[fb * VWORDS + w];
        __syncthreads();
        const int base = bs * SLICE, voff = h * VHALF;
        for (int i = base + t; i < base + SLICE; i += 256) {
            const int v = vertex[i];
            const int vk = v - voff;
            if ((unsigned)vk < (unsigned)VHALF) {
                const int e = edges[i];
                const uint_t sh = (uint_t)(vk & 1) * 16;
                const uint_t old = atomicAdd(&lds_u[vk >> 1], 1u << sh);
                col_v[rp_v[v] + (int)((old >> sh) & 0xffffu)] = e;
            }
        }
        return;
    }
    // ---- input GEMM: x0 = relu(Xin @ W0 + b0) ----
    const int lane = threadIdx.x & 63, wave = threadIdx.x >> 6;
    const int row0 = (blockIdx.x - 3 * NHB) * 64 + wave * 16;
    if (row0 >= NODES) return;
    const int r = lane & 15, kb = lane >> 4;
    const int row = row0 + r;
    bf16x8 a[4];
#pragma unroll
    for (int k0 = 0; k0 < 4; ++k0) {
        const float* p = X + (size_t)row * FIN + k0 * 32 + kb * 8;
        const float4 lo = *(const float4*)p;
        const float4 hi = *(const float4*)(p + 4);
        bf16x8 tt;
        tt[0] = f2b(lo.x); tt[1] = f2b(lo.y); tt[2] = f2b(lo.z); tt[3] = f2b(lo.w);
        tt[4] = f2b(hi.x); tt[5] = f2b(hi.y); tt[6] = f2b(hi.z); tt[7] = f2b(hi.w);
        a[k0] = tt;
    }
    f32x4 acc[8];
#pragma unroll
    for (int c0 = 0; c0 < 8; ++c0) {
        const float bv = bias[c0 * 16 + r];
        acc[c0] = (f32x4){bv, bv, bv, bv};
    }
#pragma unroll
    for (int k0 = 0; k0 < 4; ++k0)
#pragma unroll
        for (int c0 = 0; c0 < 8; ++c0) {
            const bf16x8 b = *(const bf16x8*)(Wt + (size_t)(c0 * 16 + r) * FIN + k0 * 32 + kb * 8);
            acc[c0] = __builtin_amdgcn_mfma_f32_16x16x32_bf16(a[k0], b, acc[c0], 0, 0, 0);
        }
#pragma unroll
    for (int c0 = 0; c0 < 8; ++c0) {
        const int col = c0 * 16 + r;
#pragma unroll
        for (int v = 0; v < 4; ++v) {
            const int orow = row0 + kb * 4 + v;
            float val = acc[c0][v];
            val = val > 0.f ? val : 0.f;
            x0[(size_t)orow * NHID + col] = f2b(val);
        }
    }
}

// ---- edge gather: 16 lanes/row, uint4 loads, 4 rows in flight per wave ----
__global__ __launch_bounds__(256)
void edge_gather_kernel(const ushort_t* __restrict__ x, const int* __restrict__ rp,
                        const int* __restrict__ ci, ushort_t* __restrict__ Xe,
                        float* __restrict__ out_xe) {
    const int e = (blockIdx.x * 256 + (int)threadIdx.x) >> 6;
    if (e >= EDGES) return;
    const int lane = threadIdx.x & 63;
    const int sub = lane >> 4, lr = lane & 15;
    const int beg = rp[e], end = rp[e + 1];
    float a[8] = {};
    for (int base = beg; base < end; base += 64) {
        const int m = min(64, end - base);
        const int idx_l = (lane < m) ? ci[base + lane] : 0;
        const int steps = (m + 3) >> 2;
#pragma unroll 4
        for (int j = 0; j < steps; ++j) {
            const int slot = j * 4 + sub;
            const int src = __shfl(idx_l, slot);
            if (slot < m) {
                const uint4 d = *(const uint4*)(x + (size_t)src * NHID + lr * 8);
                a[0] += u2f(d.x << 16); a[1] += u2f(d.x & 0xffff0000u);
                a[2] += u2f(d.y << 16); a[3] += u2f(d.y & 0xffff0000u);
                a[4] += u2f(d.z << 16); a[5] += u2f(d.z & 0xffff0000u);
                a[6] += u2f(d.w << 16); a[7] += u2f(d.w & 0xffff0000u);
            }
        }
    }
#pragma unroll
    for (int k = 0; k < 8; ++k) {
        a[k] += __shfl_xor(a[k], 16);
        a[k] += __shfl_xor(a[k], 32);
    }
    const float inv = 1.f / (float)max(end - beg, 1);
    if (sub == 0) {
        float vv[8];
#pragma unroll
        for (int k = 0; k < 8; ++k) vv[k] = a[k] * inv;
        uint4 o;
        o.x = pk2(vv[0], vv[1]); o.y = pk2(vv[2], vv[3]);
        o.z = pk2(vv[4], vv[5]); o.w = pk2(vv[6], vv[7]);
        *(uint4*)(Xe + (size_t)e * NHID + lr * 8) = o;
        if (out_xe) {
            const float4 f0 = {vv[0], vv[1], vv[2], vv[3]};
            const float4 f1 = {vv[4], vv[5], vv[6], vv[7]};
            *(float4*)(out_xe + (size_t)e * NHID + lr * 8) = f0;
            *(float4*)(out_xe + (size_t)e * NHID + lr * 8 + 4) = f1;
        }
    }
}

// ---- node phase 1: gather + mean + L2-normalize + residual -> Xi row in LDS ----
__device__ __forceinline__ void node_phase1(const ushort_t* __restrict__ Xe,
                                            const int* __restrict__ rp,
                                            const int* __restrict__ ci,
                                            const ushort_t* __restrict__ x0,
                                            const int vbase,
                                            ushort_t* __restrict__ xl) {
    const int lane = threadIdx.x & 63, wave = threadIdx.x >> 6;
    const int sub = lane >> 4, lr = lane & 15;
    const int row = wave * 4 + sub;
    const int v = vbase + row;
    const int beg = rp[v], end = rp[v + 1];
    const int sbase = lane & 48;
    float a[8] = {};
    for (int base = beg; base < end; base += 16) {
        const int m = min(16, end - base);
        const int idx_l = (lr < m) ? ci[base + lr] : 0;
#pragma unroll 4
        for (int j = 0; j < m; ++j) {
            const int src = __shfl(idx_l, sbase + j);
            const uint4 d = *(const uint4*)(Xe + (size_t)src * NHID + lr * 8);
            a[0] += u2f(d.x << 16); a[1] += u2f(d.x & 0xffff0000u);
            a[2] += u2f(d.y << 16); a[3] += u2f(d.y & 0xffff0000u);
            a[4] += u2f(d.z << 16); a[5] += u2f(d.z & 0xffff0000u);
            a[6] += u2f(d.w << 16); a[7] += u2f(d.w & 0xffff0000u);
        }
    }
    const float inv = 1.f / (float)max(end - beg, 1);
    float mk[8], s = 0.f;
#pragma unroll
    for (int k = 0; k < 8; ++k) { mk[k] = a[k] * inv; s += mk[k] * mk[k]; }
    s += __shfl_xor(s, 1); s += __shfl_xor(s, 2);
    s += __shfl_xor(s, 4); s += __shfl_xor(s, 8);
    const float norm = sqrtf(s);
    const float scale = norm > 0.f ? 1.f / fmaxf(norm, 1e-30f) : 0.f;
    const uint4 u0 = *(const uint4*)(x0 + (size_t)v * NHID + lr * 8);
    float xv[8];
    xv[0] = u2f(u0.x << 16); xv[1] = u2f(u0.x & 0xffff0000u);
    xv[2] = u2f(u0.y << 16); xv[3] = u2f(u0.y & 0xffff0000u);
    xv[4] = u2f(u0.z << 16); xv[5] = u2f(u0.z & 0xffff0000u);
    xv[6] = u2f(u0.w << 16); xv[7] = u2f(u0.w & 0xffff0000u);
    float o[8];
#pragma unroll
    for (int k = 0; k < 8; ++k) o[k] = 0.9f * mk[k] * scale + 0.1f * xv[k];
    uint4 ou;
    ou.x = pk2(o[0], o[1]); ou.y = pk2(o[2], o[3]);
    ou.z = pk2(o[4], o[5]); ou.w = pk2(o[6], o[7]);
    *(uint4*)(xl + row * 136 + lr * 8) = ou;
}

// ---- K6: node gather+post fused with layer-1 GEMM ----
__global__ __launch_bounds__(256)
void node_l1_kernel(const ushort_t* __restrict__ Xe, const int* __restrict__ rp,
                    const int* __restrict__ ci, const ushort_t* __restrict__ x0,
                    const ushort_t* __restrict__ Wt, float beta,
                    ushort_t* __restrict__ xout) {
    __shared__ ushort_t xl[16 * 136];
    const int vbase = blockIdx.x * 16;
    node_phase1(Xe, rp, ci, x0, vbase, xl);
    __syncthreads();
    const int lane = threadIdx.x & 63, wave = threadIdx.x >> 6;
    const int r = lane & 15, kb = lane >> 4;
    bf16x8 a2[4];
#pragma unroll
    for (int k0 = 0; k0 < 4; ++k0)
        a2[k0] = *(const bf16x8*)(xl + r * 136 + k0 * 32 + kb * 8);
    f32x4 acc[2] = {};
#pragma unroll
    for (int k0 = 0; k0 < 4; ++k0)
#pragma unroll
        for (int cc = 0; cc < 2; ++cc) {
            const int c0 = wave * 2 + cc;
            const bf16x8 b = *(const bf16x8*)(Wt + (size_t)(c0 * 16 + r) * NHID + k0 * 32 + kb * 8);
            acc[cc] = __builtin_amdgcn_mfma_f32_16x16x32_bf16(a2[k0], b, acc[cc], 0, 0, 0);
        }
    const float xim = 1.f - beta;
#pragma unroll
    for (int cc = 0; cc < 2; ++cc) {
        const int col = (wave * 2 + cc) * 16 + r;
#pragma unroll
        for (int v = 0; v < 4; ++v) {
            const int row = kb * 4 + v;
            const float xi = us2f(xl[row * 136 + col]);
            float val = xim * xi + beta * acc[cc][v];
            val = val > 0.f ? val : 0.f;
            xout[(size_t)(vbase + row) * NHID + col] = f2b(val);
        }
    }
}

// ---- K8: node gather+post fused with layer-2 GEMM AND output GEMM ----
__global__ __launch_bounds__(256)
void node_l2_out_kernel(const ushort_t* __restrict__ Xe, const int* __restrict__ rp,
                        const int* __restrict__ ci, const ushort_t* __restrict__ x0,
                        const ushort_t* __restrict__ Wt, const ushort_t* __restrict__ WoT,
                        const float* __restrict__ bias, float beta,
                        float* __restrict__ out) {
    __shared__ ushort_t xl[16 * 136];
    __shared__ ushort_t x2[16 * 136];
    const int vbase = blockIdx.x * 16;
    node_phase1(Xe, rp, ci, x0, vbase, xl);
    __syncthreads();
    const int lane = threadIdx.x & 63, wave = threadIdx.x >> 6;
    const int r = lane & 15, kb = lane >> 4;
    {
        bf16x8 a2[4];
#pragma unroll
        for (int k0 = 0; k0 < 4; ++k0)
            a2[k0] = *(const bf16x8*)(xl + r * 136 + k0 * 32 + kb * 8);
        f32x4 acc[2] = {};
#pragma unroll
        for (int k0 = 0; k0 < 4; ++k0)
#pragma unroll
            for (int cc = 0; cc < 2; ++cc) {
                const int c0 = wave * 2 + cc;
                const bf16x8 b = *(const bf16x8*)(Wt + (size_t)(c0 * 16 + r) * NHID + k0 * 32 + kb * 8);
                acc[cc] = __builtin_amdgcn_mfma_f32_16x16x32_bf16(a2[k0], b, acc[cc], 0, 0, 0);
            }
        const float xim = 1.f - beta;
#pragma unroll
        for (int cc = 0; cc < 2; ++cc) {
            const int col = (wave * 2 + cc) * 16 + r;
#pragma unroll
            for (int v = 0; v < 4; ++v) {
                const int row = kb * 4 + v;
                const float xi = us2f(xl[row * 136 + col]);
                float val = xim * xi + beta * acc[cc][v];
                val = val > 0.f ? val : 0.f;
                x2[row * 136 + col] = f2b(val);
            }
        }
    }
    __syncthreads();
    bf16x8 a3[4];
#pragma unroll
    for (int k0 = 0; k0 < 4; ++k0)
        a3[k0] = *(const bf16x8*)(x2 + r * 136 + k0 * 32 + kb * 8);
    const float bv = bias[wave * 16 + r];
    f32x4 facc = (f32x4){bv, bv, bv, bv};
#pragma unroll
    for (int k0 = 0; k0 < 4; ++k0) {
        const bf16x8 b = *(const bf16x8*)(WoT + (size_t)(wave * 16 + r) * NHID + k0 * 32 + kb * 8);
        facc = __builtin_amdgcn_mfma_f32_16x16x32_bf16(a3[k0], b, facc, 0, 0, 0);
    }
#pragma unroll
    for (int v = 0; v < 4; ++v) {
        const int row = kb * 4 + v;
        out[(size_t)(vbase + row) * FOUT + wave * 16 + r] = facc[v];
    }
}

extern "C" void kernel_launch(void* const* d_in, const int* in_sizes, int n_in,
                              void* d_out, int out_size, void* d_ws, size_t ws_size,
                              hipStream_t stream) {
    const float* x_in  = (const float*)d_in[0];
    const float* W0    = (const float*)d_in[1];
    const float* b0    = (const float*)d_in[2];
    const float* Ws    = (const float*)d_in[3];
    const float* Wout  = (const float*)d_in[4];
    const float* bout  = (const float*)d_in[5];
    const int* vertex  = (const int*)d_in[6];
    const int* edges   = (const int*)d_in[7];

    ushort_t* Xe   = (ushort_t*)d_ws;                       // EDGES*NHID bf16
    ushort_t* x    = Xe + (size_t)EDGES * NHID;             // NODES*NHID bf16
    ushort_t* x0   = x  + (size_t)NODES * NHID;             // NODES*NHID bf16
    ushort_t* Wt0  = x0 + (size_t)NODES * NHID;             // 128*128
    ushort_t* WsT  = Wt0 + 128 * 128;                       // 2*128*128
    ushort_t* WoutT= WsT + 2 * 128 * 128;                   // 64*128
    // (ushort total = 14,137,344 -> byte offset 28,274,688, 16B-aligned)
    int* cnt_e = (int*)(WoutT + 64 * 128);                  // EDGES        (16B-aligned)
    int* cnt_v = cnt_e + EDGES;                             // NODES        (16B-aligned)
    int* rp_e  = cnt_v + NODES;                             // EDGES+1 (pad to 10004)
    int* rp_v  = rp_e + EDGES + 4;                          // NODES+1 (pad to 50004)
    uint_t* cbe = (uint_t*)(rp_v + NODES + 4);              // NHB*EDGES      = 1.28M
    uint_t* cbv = cbe + (size_t)NHB * EDGES;                // 2*NHB*VWORDS   = 3.20M
    int* col_e = (int*)(cbv + (size_t)2 * NHB * VWORDS);    // NNZ
    int* col_v = col_e + NNZ;                               // NNZ

    float* out    = (float*)d_out;                          // [NODES, FOUT]
    float* out_xe = out + (size_t)NODES * FOUT;             // [EDGES, NHID]

    // K1: LDS histograms (edge + vertex) + weight conversion  (no global atomics)
    hist_wconv_kernel<<<3 * NHB + WCONV_BLOCKS, 256, 0, stream>>>(
        vertex, edges, cbe, cbv, W0, Ws, Wout, Wt0, WsT, WoutT);
    // K2a: per-key scan over block counts -> block bases + totals
    colscan_kernel<<<(EDGES + 2 * VWORDS + 255) / 256, 256, 0, stream>>>(
        cbe, cbv, cnt_e, cnt_v);
    // K2b: rp scans
    scan2_kernel<<<2, 1024, 0, stream>>>(cnt_e, rp_e, cnt_v, rp_v);
    // K3: fill both CSRs (LDS cursors) + input GEMM
    fill_gemm_kernel<<<3 * NHB + GEMM_BLOCKS, 256, 0, stream>>>(
        vertex, edges, cbe, cbv, rp_e, rp_v, col_e, col_v, x_in, Wt0, b0, x0);

    const float betas[2] = {logf(1.5f), logf(1.25f)};  // log(0.5/(i+1)+1)

    // layer 1
    edge_gather_kernel<<<EDGE_BLOCKS, 256, 0, stream>>>(x0, rp_e, col_e, Xe, (float*)nullptr);
    node_l1_kernel<<<NF_BLOCKS, 256, 0, stream>>>(Xe, rp_v, col_v, x0, WsT, betas[0], x);
    // layer 2
    edge_gather_kernel<<<EDGE_BLOCKS, 256, 0, stream>>>(x, rp_e, col_e, Xe, out_xe);
    node_l2_out_kernel<<<NF_BLOCKS, 256, 0, stream>>>(
        Xe, rp_v, col_v, x0, WsT + (size_t)NHID * NHID, WoutT, bout, betas[1], out);
}

// Round 12
// 211.249 us; speedup vs baseline: 2.2006x; 1.0102x over previous
//
#include <hip/hip_runtime.h>
#include <hip/hip_bf16.h>
#include <math.h>

#define NODES 50000
#define EDGES 10000
#define NNZ   800000
#define FIN   128
#define NHID  128
#define FOUT  64

#define NHB      128               // hist/fill blocks per slice pass
#define SLICE    (NNZ / NHB)       // 6250 entries per block slice
#define EWORDS   (EDGES / 2)       // 5000 packed words (edge counters, u16 x2)
#define VQUARTER 12500             // vertex keys per quarter
#define QWORDS   (VQUARTER / 2)    // 6250 packed words per quarter

#define WCONV_BLOCKS 128
#define GEMM_BLOCKS  ((NODES + 63) / 64)  // 782
#define EDGE_BLOCKS  (EDGES * 64 / 256)   // 2500
#define NF_BLOCKS    (NODES / 16)         // 3125

typedef __attribute__((ext_vector_type(8))) short bf16x8;
typedef __attribute__((ext_vector_type(4))) float f32x4;
typedef unsigned short ushort_t;
typedef unsigned int uint_t;

__device__ __forceinline__ ushort_t f2b(float f) {
    __hip_bfloat16 h = __float2bfloat16(f);
    return *reinterpret_cast<ushort_t*>(&h);
}
__device__ __forceinline__ float u2f(unsigned u) {
    union { unsigned u; float f; } c; c.u = u; return c.f;
}
__device__ __forceinline__ float us2f(ushort_t u) { return u2f((unsigned)u << 16); }
__device__ __forceinline__ unsigned pk2(float lo, float hi) {
    return (unsigned)f2b(lo) | ((unsigned)f2b(hi) << 16);
}

// ---- K1: LDS histograms, u16-packed (edge | vertex quarters) | wconv ----
__global__ __launch_bounds__(256)
void hist_wconv_kernel(const int* __restrict__ vertex, const int* __restrict__ edges,
                       uint_t* __restrict__ cbe, uint_t* __restrict__ cbv,
                       const float* __restrict__ W0, const float* __restrict__ Ws,
                       const float* __restrict__ Wout,
                       ushort_t* __restrict__ Wt0, ushort_t* __restrict__ WsT,
                       ushort_t* __restrict__ WoutT) {
    __shared__ uint_t lds_u[QWORDS];   // 25 KB
    const int t = threadIdx.x;
    if (blockIdx.x < NHB) {                      // ---- edge histogram (packed) ----
        const int b = blockIdx.x;
        for (int w = t; w < EWORDS; w += 256) lds_u[w] = 0;
        __syncthreads();
        const int base = b * SLICE;
        for (int i = base + t; i < base + SLICE; i += 256) {
            const int e = edges[i];
            atomicAdd(&lds_u[e >> 1], 1u << ((e & 1) * 16));
        }
        __syncthreads();
        for (int w = t; w < EWORDS; w += 256) cbe[b * EWORDS + w] = lds_u[w];
    } else if (blockIdx.x < NHB + 4 * NHB) {     // ---- vertex histogram (4 quarters) ----
        const int qb = blockIdx.x - NHB, q = qb >> 7, bs = qb & 127;
        for (int w = t; w < QWORDS; w += 256) lds_u[w] = 0;
        __syncthreads();
        const int base = bs * SLICE, voff = q * VQUARTER;
        for (int i = base + t; i < base + SLICE; i += 256) {
            const int vk = vertex[i] - voff;
            if ((unsigned)vk < (unsigned)VQUARTER)
                atomicAdd(&lds_u[vk >> 1], 1u << ((vk & 1) * 16));
        }
        __syncthreads();
        for (int w = t; w < QWORDS; w += 256) cbv[qb * QWORDS + w] = lds_u[w];
    } else {                                     // ---- weight transpose/convert ----
        const int i = (blockIdx.x - 5 * NHB) * 256 + t;
        if (i < 128 * 128) { int c = i >> 7, k = i & 127; Wt0[c * 128 + k] = f2b(W0[k * 128 + c]); }
        if (i < 2 * 128 * 128) {
            int l = i >> 14, r = i & 16383, c = r >> 7, k = r & 127;
            WsT[l * 16384 + c * 128 + k] = f2b(Ws[l * 16384 + k * 128 + c]);
        }
        if (i < 64 * 128) { int c = i >> 7, k = i & 127; WoutT[c * 128 + k] = f2b(Wout[k * 64 + c]); }
    }
}

// ---- K2a: per-key exclusive scan over block counts (packed columns) ----
__global__ __launch_bounds__(256)
void colscan_kernel(uint_t* __restrict__ cbe, uint_t* __restrict__ cbv,
                    int* __restrict__ cnt_e, int* __restrict__ cnt_v) {
    const int flat = blockIdx.x * 256 + threadIdx.x;
    if (flat < EWORDS) {
        uint_t s0 = 0, s1 = 0;
        for (int b = 0; b < NHB; ++b) {
            uint_t* p = &cbe[b * EWORDS + flat];
            const uint_t u = *p; *p = s0 | (s1 << 16);
            s0 += u & 0xffffu; s1 += u >> 16;
        }
        cnt_e[2 * flat]     = (int)s0;
        cnt_e[2 * flat + 1] = (int)s1;
    } else if (flat < EWORDS + 4 * QWORDS) {
        const int idx = flat - EWORDS, q = idx / QWORDS, w = idx % QWORDS;
        uint_t s0 = 0, s1 = 0;
        for (int bs = 0; bs < NHB; ++bs) {
            uint_t* p = &cbv[(q * NHB + bs) * QWORDS + w];
            const uint_t u = *p; *p = s0 | (s1 << 16);
            s0 += u & 0xffffu; s1 += u >> 16;
        }
        cnt_v[q * VQUARTER + 2 * w]     = (int)s0;
        cnt_v[q * VQUARTER + 2 * w + 1] = (int)s1;
    }
}

// ---- exclusive scan, 8 items/thread, single 1024-thread block ----
__device__ __forceinline__ void scan_impl(const int* __restrict__ cnt, int* __restrict__ rp,
                                          const int n) {
    __shared__ int wsum[16];
    __shared__ int carry_sh;
    const int t = threadIdx.x, lane = t & 63, w = t >> 6;
    if (t == 0) carry_sh = 0;
    __syncthreads();
    for (int base = 0; base < n; base += 8192) {
        const int idx = base + t * 8;
        int v[8];
        if (idx + 8 <= n) {
            const int4 a = *(const int4*)(cnt + idx);
            const int4 b = *(const int4*)(cnt + idx + 4);
            v[0] = a.x; v[1] = a.y; v[2] = a.z; v[3] = a.w;
            v[4] = b.x; v[5] = b.y; v[6] = b.z; v[7] = b.w;
        } else {
#pragma unroll
            for (int j = 0; j < 8; ++j) v[j] = (idx + j < n) ? cnt[idx + j] : 0;
        }
        int sum8 = 0;
#pragma unroll
        for (int j = 0; j < 8; ++j) sum8 += v[j];
        int x = sum8;
#pragma unroll
        for (int o = 1; o < 64; o <<= 1) {
            int y = __shfl_up(x, o);
            if (lane >= o) x += y;
        }
        if (lane == 63) wsum[w] = x;
        __syncthreads();
        if (t < 16) {
            int s = wsum[t];
#pragma unroll
            for (int o = 1; o < 16; o <<= 1) {
                int y = __shfl_up(s, o);
                if (t >= o) s += y;
            }
            wsum[t] = s;
        }
        __syncthreads();
        const int carry = carry_sh;
        int pre = carry + (x - sum8) + (w ? wsum[w - 1] : 0);
        if (idx < n) {
#pragma unroll
            for (int j = 0; j < 8; ++j)
                if (idx + j < n) { rp[idx + j] = pre; pre += v[j]; }
        }
        __syncthreads();
        if (t == 1023) carry_sh = carry + wsum[15];
        __syncthreads();
    }
    if (t == 0) rp[n] = carry_sh;
}

// ---- K2b: both rp scans in one launch ----
__global__ __launch_bounds__(1024)
void scan2_kernel(const int* __restrict__ cnt_e, int* __restrict__ rp_e,
                  const int* __restrict__ cnt_v, int* __restrict__ rp_v) {
    if (blockIdx.x == 0) scan_impl(cnt_e, rp_e, EDGES);
    else                 scan_impl(cnt_v, rp_v, NODES);
}

// ---- K3: fill edge-CSR + fill vertex-CSR (packed LDS cursors) | input GEMM ----
__global__ __launch_bounds__(256)
void fill_gemm_kernel(const int* __restrict__ vertex, const int* __restrict__ edges,
                      const uint_t* __restrict__ cbe, const uint_t* __restrict__ cbv,
                      const int* __restrict__ rp_e, const int* __restrict__ rp_v,
                      ushort_t* __restrict__ col_e, ushort_t* __restrict__ col_v,
                      const float* __restrict__ X, const ushort_t* __restrict__ Wt,
                      const float* __restrict__ bias, ushort_t* __restrict__ x0) {
    __shared__ uint_t lds_u[QWORDS];
    const int t = threadIdx.x;
    if (blockIdx.x < NHB) {                      // ---- fill edge-CSR ----
        const int b = blockIdx.x;
        for (int w = t; w < EWORDS; w += 256) lds_u[w] = cbe[b * EWORDS + w];
        __syncthreads();
        const int base = b * SLICE;
        for (int i = base + t; i < base + SLICE; i += 256) {
            const int e = edges[i], v = vertex[i];
            const uint_t sh = (uint_t)(e & 1) * 16;
            const uint_t old = atomicAdd(&lds_u[e >> 1], 1u << sh);
            col_e[rp_e[e] + (int)((old >> sh) & 0xffffu)] = (ushort_t)v;
        }
        return;
    }
    if (blockIdx.x < 5 * NHB) {                  // ---- fill vertex-CSR (4 quarters) ----
        const int qb = blockIdx.x - NHB, q = qb >> 7, bs = qb & 127;
        for (int w = t; w < QWORDS; w += 256) lds_u[w] = cbv[qb * QWORDS + w];
        __syncthreads();
        const int base = bs * SLICE, voff = q * VQUARTER;
        for (int i = base + t; i < base + SLICE; i += 256) {
            const int v = vertex[i];
            const int vk = v - voff;
            if ((unsigned)vk < (unsigned)VQUARTER) {
                const int e = edges[i];
                const uint_t sh = (uint_t)(vk & 1) * 16;
                const uint_t old = atomicAdd(&lds_u[vk >> 1], 1u << sh);
                col_v[rp_v[v] + (int)((old >> sh) & 0xffffu)] = (ushort_t)e;
            }
        }
        return;
    }
    // ---- input GEMM: x0 = relu(Xin @ W0 + b0) ----
    const int lane = threadIdx.x & 63, wave = threadIdx.x >> 6;
    const int row0 = (blockIdx.x - 5 * NHB) * 64 + wave * 16;
    if (row0 >= NODES) return;
    const int r = lane & 15, kb = lane >> 4;
    const int row = row0 + r;
    bf16x8 a[4];
#pragma unroll
    for (int k0 = 0; k0 < 4; ++k0) {
        const float* p = X + (size_t)row * FIN + k0 * 32 + kb * 8;
        const float4 lo = *(const float4*)p;
        const float4 hi = *(const float4*)(p + 4);
        bf16x8 tt;
        tt[0] = f2b(lo.x); tt[1] = f2b(lo.y); tt[2] = f2b(lo.z); tt[3] = f2b(lo.w);
        tt[4] = f2b(hi.x); tt[5] = f2b(hi.y); tt[6] = f2b(hi.z); tt[7] = f2b(hi.w);
        a[k0] = tt;
    }
    f32x4 acc[8];
#pragma unroll
    for (int c0 = 0; c0 < 8; ++c0) {
        const float bv = bias[c0 * 16 + r];
        acc[c0] = (f32x4){bv, bv, bv, bv};
    }
#pragma unroll
    for (int k0 = 0; k0 < 4; ++k0)
#pragma unroll
        for (int c0 = 0; c0 < 8; ++c0) {
            const bf16x8 b = *(const bf16x8*)(Wt + (size_t)(c0 * 16 + r) * FIN + k0 * 32 + kb * 8);
            acc[c0] = __builtin_amdgcn_mfma_f32_16x16x32_bf16(a[k0], b, acc[c0], 0, 0, 0);
        }
#pragma unroll
    for (int c0 = 0; c0 < 8; ++c0) {
        const int col = c0 * 16 + r;
#pragma unroll
        for (int v = 0; v < 4; ++v) {
            const int orow = row0 + kb * 4 + v;
            float val = acc[c0][v];
            val = val > 0.f ? val : 0.f;
            x0[(size_t)orow * NHID + col] = f2b(val);
        }
    }
}

// ---- edge gather: 16 lanes/row, uint4 loads, 4 rows in flight per wave ----
__global__ __launch_bounds__(256)
void edge_gather_kernel(const ushort_t* __restrict__ x, const int* __restrict__ rp,
                        const ushort_t* __restrict__ ci, ushort_t* __restrict__ Xe,
                        float* __restrict__ out_xe) {
    const int e = (blockIdx.x * 256 + (int)threadIdx.x) >> 6;
    if (e >= EDGES) return;
    const int lane = threadIdx.x & 63;
    const int sub = lane >> 4, lr = lane & 15;
    const int beg = rp[e], end = rp[e + 1];
    float a[8] = {};
    for (int base = beg; base < end; base += 64) {
        const int m = min(64, end - base);
        const int idx_l = (lane < m) ? (int)ci[base + lane] : 0;
        const int steps = (m + 3) >> 2;
#pragma unroll 4
        for (int j = 0; j < steps; ++j) {
            const int slot = j * 4 + sub;
            const int src = __shfl(idx_l, slot);
            if (slot < m) {
                const uint4 d = *(const uint4*)(x + (size_t)src * NHID + lr * 8);
                a[0] += u2f(d.x << 16); a[1] += u2f(d.x & 0xffff0000u);
                a[2] += u2f(d.y << 16); a[3] += u2f(d.y & 0xffff0000u);
                a[4] += u2f(d.z << 16); a[5] += u2f(d.z & 0xffff0000u);
                a[6] += u2f(d.w << 16); a[7] += u2f(d.w & 0xffff0000u);
            }
        }
    }
#pragma unroll
    for (int k = 0; k < 8; ++k) {
        a[k] += __shfl_xor(a[k], 16);
        a[k] += __shfl_xor(a[k], 32);
    }
    const float inv = 1.f / (float)max(end - beg, 1);
    if (sub == 0) {
        float vv[8];
#pragma unroll
        for (int k = 0; k < 8; ++k) vv[k] = a[k] * inv;
        uint4 o;
        o.x = pk2(vv[0], vv[1]); o.y = pk2(vv[2], vv[3]);
        o.z = pk2(vv[4], vv[5]); o.w = pk2(vv[6], vv[7]);
        *(uint4*)(Xe + (size_t)e * NHID + lr * 8) = o;
        if (out_xe) {
            const float4 f0 = {vv[0], vv[1], vv[2], vv[3]};
            const float4 f1 = {vv[4], vv[5], vv[6], vv[7]};
            *(float4*)(out_xe + (size_t)e * NHID + lr * 8) = f0;
            *(float4*)(out_xe + (size_t)e * NHID + lr * 8 + 4) = f1;
        }
    }
}

// ---- node phase 1: gather + mean + L2-normalize + residual -> Xi row in LDS ----
__device__ __forceinline__ void node_phase1(const ushort_t* __restrict__ Xe,
                                            const int* __restrict__ rp,
                                            const ushort_t* __restrict__ ci,
                                            const ushort_t* __restrict__ x0,
                                            const int vbase,
                                            ushort_t* __restrict__ xl) {
    const int lane = threadIdx.x & 63, wave = threadIdx.x >> 6;
    const int sub = lane >> 4, lr = lane & 15;
    const int row = wave * 4 + sub;
    const int v = vbase + row;
    const int beg = rp[v], end = rp[v + 1];
    const int sbase = lane & 48;
    float a[8] = {};
    for (int base = beg; base < end; base += 16) {
        const int m = min(16, end - base);
        const int idx_l = (lr < m) ? (int)ci[base + lr] : 0;
#pragma unroll 4
        for (int j = 0; j < m; ++j) {
            const int src = __shfl(idx_l, sbase + j);
            const uint4 d = *(const uint4*)(Xe + (size_t)src * NHID + lr * 8);
            a[0] += u2f(d.x << 16); a[1] += u2f(d.x & 0xffff0000u);
            a[2] += u2f(d.y << 16); a[3] += u2f(d.y & 0xffff0000u);
            a[4] += u2f(d.z << 16); a[5] += u2f(d.z & 0xffff0000u);
            a[6] += u2f(d.w << 16); a[7] += u2f(d.w & 0xffff0000u);
        }
    }
    const float inv = 1.f / (float)max(end - beg, 1);
    float mk[8], s = 0.f;
#pragma unroll
    for (int k = 0; k < 8; ++k) { mk[k] = a[k] * inv; s += mk[k] * mk[k]; }
    s += __shfl_xor(s, 1); s += __shfl_xor(s, 2);
    s += __shfl_xor(s, 4); s += __shfl_xor(s, 8);
    const float norm = sqrtf(s);
    const float scale = norm > 0.f ? 1.f / fmaxf(norm, 1e-30f) : 0.f;
    const uint4 u0 = *(const uint4*)(x0 + (size_t)v * NHID + lr * 8);
    float xv[8];
    xv[0] = u2f(u0.x << 16); xv[1] = u2f(u0.x & 0xffff0000u);
    xv[2] = u2f(u0.y << 16); xv[3] = u2f(u0.y & 0xffff0000u);
    xv[4] = u2f(u0.z << 16); xv[5] = u2f(u0.z & 0xffff0000u);
    xv[6] = u2f(u0.w << 16); xv[7] = u2f(u0.w & 0xffff0000u);
    float o[8];
#pragma unroll
    for (int k = 0; k < 8; ++k) o[k] = 0.9f * mk[k] * scale + 0.1f * xv[k];
    uint4 ou;
    ou.x = pk2(o[0], o[1]); ou.y = pk2(o[2], o[3]);
    ou.z = pk2(o[4], o[5]); ou.w = pk2(o[6], o[7]);
    *(uint4*)(xl + row * 136 + lr * 8) = ou;
}

// ---- K6: node gather+post fused with layer-1 GEMM ----
__global__ __launch_bounds__(256)
void node_l1_kernel(const ushort_t* __restrict__ Xe, const int* __restrict__ rp,
                    const ushort_t* __restrict__ ci, const ushort_t* __restrict__ x0,
                    const ushort_t* __restrict__ Wt, float beta,
                    ushort_t* __restrict__ xout) {
    __shared__ ushort_t xl[16 * 136];
    const int vbase = blockIdx.x * 16;
    node_phase1(Xe, rp, ci, x0, vbase, xl);
    __syncthreads();
    const int lane = threadIdx.x & 63, wave = threadIdx.x >> 6;
    const int r = lane & 15, kb = lane >> 4;
    bf16x8 a2[4];
#pragma unroll
    for (int k0 = 0; k0 < 4; ++k0)
        a2[k0] = *(const bf16x8*)(xl + r * 136 + k0 * 32 + kb * 8);
    f32x4 acc[2] = {};
#pragma unroll
    for (int k0 = 0; k0 < 4; ++k0)
#pragma unroll
        for (int cc = 0; cc < 2; ++cc) {
            const int c0 = wave * 2 + cc;
            const bf16x8 b = *(const bf16x8*)(Wt + (size_t)(c0 * 16 + r) * NHID + k0 * 32 + kb * 8);
            acc[cc] = __builtin_amdgcn_mfma_f32_16x16x32_bf16(a2[k0], b, acc[cc], 0, 0, 0);
        }
    const float xim = 1.f - beta;
#pragma unroll
    for (int cc = 0; cc < 2; ++cc) {
        const int col = (wave * 2 + cc) * 16 + r;
#pragma unroll
        for (int v = 0; v < 4; ++v) {
            const int row = kb * 4 + v;
            const float xi = us2f(xl[row * 136 + col]);
            float val = xim * xi + beta * acc[cc][v];
            val = val > 0.f ? val : 0.f;
            xout[(size_t)(vbase + row) * NHID + col] = f2b(val);
        }
    }
}

// ---- K8: node gather+post fused with layer-2 GEMM AND output GEMM ----
__global__ __launch_bounds__(256)
void node_l2_out_kernel(const ushort_t* __restrict__ Xe, const int* __restrict__ rp,
                        const ushort_t* __restrict__ ci, const ushort_t* __restrict__ x0,
                        const ushort_t* __restrict__ Wt, const ushort_t* __restrict__ WoT,
                        const float* __restrict__ bias, float beta,
                        float* __restrict__ out) {
    __shared__ ushort_t xl[16 * 136];
    __shared__ ushort_t x2[16 * 136];
    const int vbase = blockIdx.x * 16;
    node_phase1(Xe, rp, ci, x0, vbase, xl);
    __syncthreads();
    const int lane = threadIdx.x & 63, wave = threadIdx.x >> 6;
    const int r = lane & 15, kb = lane >> 4;
    {
        bf16x8 a2[4];
#pragma unroll
        for (int k0 = 0; k0 < 4; ++k0)
            a2[k0] = *(const bf16x8*)(xl + r * 136 + k0 * 32 + kb * 8);
        f32x4 acc[2] = {};
#pragma unroll
        for (int k0 = 0; k0 < 4; ++k0)
#pragma unroll
            for (int cc = 0; cc < 2; ++cc) {
                const int c0 = wave * 2 + cc;
                const bf16x8 b = *(const bf16x8*)(Wt + (size_t)(c0 * 16 + r) * NHID + k0 * 32 + kb * 8);
                acc[cc] = __builtin_amdgcn_mfma_f32_16x16x32_bf16(a2[k0], b, acc[cc], 0, 0, 0);
            }
        const float xim = 1.f - beta;
#pragma unroll
        for (int cc = 0; cc < 2; ++cc) {
            const int col = (wave * 2 + cc) * 16 + r;
#pragma unroll
            for (int v = 0; v < 4; ++v) {
                const int row = kb * 4 + v;
                const float xi = us2f(xl[row * 136 + col]);
                float val = xim * xi + beta * acc[cc][v];
                val = val > 0.f ? val : 0.f;
                x2[row * 136 + col] = f2b(val);
            }
        }
    }
    __syncthreads();
    bf16x8 a3[4];
#pragma unroll
    for (int k0 = 0; k0 < 4; ++k0)
        a3[k0] = *(const bf16x8*)(x2 + r * 136 + k0 * 32 + kb * 8);
    const float bv = bias[wave * 16 + r];
    f32x4 facc = (f32x4){bv, bv, bv, bv};
#pragma unroll
    for (int k0 = 0; k0 < 4; ++k0) {
        const bf16x8 b = *(const bf16x8*)(WoT + (size_t)(wave * 16 + r) * NHID + k0 * 32 + kb * 8);
        facc = __builtin_amdgcn_mfma_f32_16x16x32_bf16(a3[k0], b, facc, 0, 0, 0);
    }
#pragma unroll
    for (int v = 0; v < 4; ++v) {
        const int row = kb * 4 + v;
        out[(size_t)(vbase + row) * FOUT + wave * 16 + r] = facc[v];
    }
}

extern "C" void kernel_launch(void* const* d_in, const int* in_sizes, int n_in,
                              void* d_out, int out_size, void* d_ws, size_t ws_size,
                              hipStream_t stream) {
    const float* x_in  = (const float*)d_in[0];
    const float* W0    = (const float*)d_in[1];
    const float* b0    = (const float*)d_in[2];
    const float* Ws    = (const float*)d_in[3];
    const float* Wout  = (const float*)d_in[4];
    const float* bout  = (const float*)d_in[5];
    const int* vertex  = (const int*)d_in[6];
    const int* edges   = (const int*)d_in[7];

    ushort_t* Xe   = (ushort_t*)d_ws;                       // EDGES*NHID bf16
    ushort_t* x    = Xe + (size_t)EDGES * NHID;             // NODES*NHID bf16
    ushort_t* x0   = x  + (size_t)NODES * NHID;             // NODES*NHID bf16
    ushort_t* Wt0  = x0 + (size_t)NODES * NHID;             // 128*128
    ushort_t* WsT  = Wt0 + 128 * 128;                       // 2*128*128
    ushort_t* WoutT= WsT + 2 * 128 * 128;                   // 64*128
    int* cnt_e = (int*)(WoutT + 64 * 128);                  // EDGES
    int* cnt_v = cnt_e + EDGES;                             // NODES
    int* rp_e  = cnt_v + NODES;                             // EDGES+1 (pad to 10004)
    int* rp_v  = rp_e + EDGES + 4;                          // NODES+1 (pad to 50004)
    uint_t* cbe = (uint_t*)(rp_v + NODES + 4);              // NHB*EWORDS   = 640K words
    uint_t* cbv = cbe + (size_t)NHB * EWORDS;               // 4*NHB*QWORDS = 3.2M words
    ushort_t* col_e = (ushort_t*)(cbv + (size_t)4 * NHB * QWORDS);  // NNZ u16
    ushort_t* col_v = col_e + NNZ;                          // NNZ u16

    float* out    = (float*)d_out;                          // [NODES, FOUT]
    float* out_xe = out + (size_t)NODES * FOUT;             // [EDGES, NHID]

    // K1: LDS histograms (edge + 4 vertex quarters) + weight conversion
    hist_wconv_kernel<<<5 * NHB + WCONV_BLOCKS, 256, 0, stream>>>(
        vertex, edges, cbe, cbv, W0, Ws, Wout, Wt0, WsT, WoutT);
    // K2a: per-key scan over block counts -> block bases + totals
    colscan_kernel<<<(EWORDS + 4 * QWORDS + 255) / 256, 256, 0, stream>>>(
        cbe, cbv, cnt_e, cnt_v);
    // K2b: rp scans
    scan2_kernel<<<2, 1024, 0, stream>>>(cnt_e, rp_e, cnt_v, rp_v);
    // K3: fill both CSRs (packed LDS cursors) + input GEMM
    fill_gemm_kernel<<<5 * NHB + GEMM_BLOCKS, 256, 0, stream>>>(
        vertex, edges, cbe, cbv, rp_e, rp_v, col_e, col_v, x_in, Wt0, b0, x0);

    const float betas[2] = {logf(1.5f), logf(1.25f)};  // log(0.5/(i+1)+1)

    // layer 1
    edge_gather_kernel<<<EDGE_BLOCKS, 256, 0, stream>>>(x0, rp_e, col_e, Xe, (float*)nullptr);
    node_l1_kernel<<<NF_BLOCKS, 256, 0, stream>>>(Xe, rp_v, col_v, x0, WsT, betas[0], x);
    // layer 2
    edge_gather_kernel<<<EDGE_BLOCKS, 256, 0, stream>>>(x, rp_e, col_e, Xe, out_xe);
    node_l2_out_kernel<<<NF_BLOCKS, 256, 0, stream>>>(
        Xe, rp_v, col_v, x0, WsT + (size_t)NHID * NHID, WoutT, bout, betas[1], out);
}